// Round 4
// baseline (342.202 us; speedup 1.0000x reference)
//
#include <hip/hip_runtime.h>

// Problem constants
#define NB   8        // batch
#define NPT  8192     // N query points
#define NS   2048     // S source points
#define ND1  128      // points1 channels
#define ND2  256      // points2 channels
#define NIN  384      // concat channels
#define NC0  256      // MLP[0]
#define NC1  128      // MLP[1]
#define NBN  (NB*NPT) // 65536 total columns

typedef __bf16 bf16x8 __attribute__((ext_vector_type(8)));
typedef __bf16 bf16x4 __attribute__((ext_vector_type(4)));
typedef float  f32x4  __attribute__((ext_vector_type(4)));

// ---------------------------------------------------------------------------
// Kernel 1: 3-NN + inverse-distance weights.
// grid (NB, 128): 64 queries/block, 256 thr. Thread = (query-pair, part):
// 2 queries/thread, 8 parts x 256 candidates. One ds_read_b128 feeds TWO
// top-3 updates (halves LDS traffic); unroll 4 keeps 4 reads in flight
// (hides ~120cy LDS latency). part = tid>>5 -> wave spans 2 broadcast
// addresses (free). Sorted-triple value update via v_med3_f32 (1 instr).
// md/mi merge buffers overlay pts' LDS after the scan (keeps 32KB -> 4 blk/CU).
// ---------------------------------------------------------------------------
__global__ __launch_bounds__(256) void knn_kernel(
    const float* __restrict__ xyz1, const float* __restrict__ xyz2,
    int* __restrict__ idx3, float* __restrict__ wgt3)
{
    __shared__ float4 pts[NS];      // 32 KB; overlaid by md/mi after scan

    const int b  = blockIdx.x;
    const int qt = blockIdx.y;
    const float* x2 = xyz2 + (size_t)b * 3 * NS;
    for (int s = threadIdx.x; s < NS; s += 256) {
        float x = x2[s], y = x2[NS + s], z = x2[2 * NS + s];
        pts[s] = make_float4(x, y, z, x * x + y * y + z * z);
    }
    __syncthreads();

    const int qg   = threadIdx.x & 31;   // query pair 0..31
    const int part = threadIdx.x >> 5;   // 0..7
    const int n0   = qt * 64 + qg * 2;
    const float* x1 = xyz1 + (size_t)b * 3 * NPT;
    const float ax = x1[n0],     ay = x1[NPT + n0],     az = x1[2 * NPT + n0];
    const float bx = x1[n0 + 1], by = x1[NPT + n0 + 1], bz = x1[2 * NPT + n0 + 1];

    float ad0 = 3e38f, ad1 = 3e38f, ad2 = 3e38f;
    float bd0 = 3e38f, bd1 = 3e38f, bd2 = 3e38f;
    int   ai0 = 0, ai1 = 0, ai2 = 0;
    int   bi0 = 0, bi1 = 0, bi2 = 0;

    const int sbeg = part * 256;
    #pragma unroll 4
    for (int s = sbeg; s < sbeg + 256; ++s) {
        float4 p = pts[s];
        // query A: key = |p2|^2 - 2 p1.p2  (|p1|^2 re-added at the end)
        float ta = ax * p.x; ta = fmaf(ay, p.y, ta); ta = fmaf(az, p.z, ta);
        float da = fmaf(-2.f, ta, p.w);
        {
            bool c0 = da < ad0, c1 = da < ad1, c2 = da < ad2;
            ai2 = c1 ? ai1 : (c2 ? s : ai2);
            ai1 = c0 ? ai0 : (c1 ? s : ai1);
            ai0 = c0 ? s : ai0;
            float m2, m1;
            asm("v_med3_f32 %0, %1, %2, %3" : "=v"(m2) : "v"(da), "v"(ad1), "v"(ad2));
            asm("v_med3_f32 %0, %1, %2, %3" : "=v"(m1) : "v"(da), "v"(ad0), "v"(ad1));
            ad2 = m2; ad1 = m1; ad0 = fminf(da, ad0);
        }
        // query B
        float tb = bx * p.x; tb = fmaf(by, p.y, tb); tb = fmaf(bz, p.z, tb);
        float db = fmaf(-2.f, tb, p.w);
        {
            bool c0 = db < bd0, c1 = db < bd1, c2 = db < bd2;
            bi2 = c1 ? bi1 : (c2 ? s : bi2);
            bi1 = c0 ? bi0 : (c1 ? s : bi1);
            bi0 = c0 ? s : bi0;
            float m2, m1;
            asm("v_med3_f32 %0, %1, %2, %3" : "=v"(m2) : "v"(db), "v"(bd1), "v"(bd2));
            asm("v_med3_f32 %0, %1, %2, %3" : "=v"(m1) : "v"(db), "v"(bd0), "v"(bd1));
            bd2 = m2; bd1 = m1; bd0 = fminf(db, bd0);
        }
    }
    __syncthreads();                     // all pts reads done -> overlay safe

    float* md = (float*)pts;             // [64][8][3] = 6 KB
    int*   mi = (int*)pts + 64 * 8 * 3;  // [64][8][3] = 6 KB
    {
        const int q0 = qg * 2;
        int base = (q0 * 8 + part) * 3;
        md[base] = ad0; md[base + 1] = ad1; md[base + 2] = ad2;
        mi[base] = ai0; mi[base + 1] = ai1; mi[base + 2] = ai2;
        base += 24;                      // query q0+1
        md[base] = bd0; md[base + 1] = bd1; md[base + 2] = bd2;
        mi[base] = bi0; mi[base + 1] = bi1; mi[base + 2] = bi2;
    }
    __syncthreads();

    if (threadIdx.x < 64) {
        const int q = threadIdx.x;
        const int n = qt * 64 + q;
        // 8-way merge of sorted triples; ascending part + strict < keeps
        // lowest s on ties (parts are s-ordered) = top_k tie-break.
        int hp[8] = {0, 0, 0, 0, 0, 0, 0, 0};
        float rd[3]; int ri[3];
        #pragma unroll
        for (int k = 0; k < 3; ++k) {
            float best = 3.0e38f; int bl = 0;
            #pragma unroll
            for (int l = 0; l < 8; ++l) {
                float dv = md[(q * 8 + l) * 3 + hp[l]];
                if (dv < best) { best = dv; bl = l; }
            }
            rd[k] = best; ri[k] = mi[(q * 8 + bl) * 3 + hp[bl]];
            #pragma unroll
            for (int l = 0; l < 8; ++l) if (l == bl) hp[l]++;
        }
        const float px = x1[n], py = x1[NPT + n], pz = x1[2 * NPT + n];
        const float p1sq = px * px + py * py + pz * pz;
        float r0 = 1.0f / (rd[0] + p1sq + 1e-8f);
        float r1 = 1.0f / (rd[1] + p1sq + 1e-8f);
        float r2 = 1.0f / (rd[2] + p1sq + 1e-8f);
        float inv = 1.0f / (r0 + r1 + r2);
        size_t base = ((size_t)b * NPT + n) * 3;
        idx3[base] = ri[0]; idx3[base + 1] = ri[1]; idx3[base + 2] = ri[2];
        wgt3[base] = r0 * inv; wgt3[base + 1] = r1 * inv; wgt3[base + 2] = r2 * inv;
    }
}

// ---------------------------------------------------------------------------
// Kernel 2: transpose points2 [b][d][s] fp32 -> p2t [b][s][d] bf16.
// ---------------------------------------------------------------------------
__global__ __launch_bounds__(256) void transpose_p2_kernel(
    const float* __restrict__ p2, __bf16* __restrict__ p2t)
{
    __shared__ float tile[64][65];
    const int b  = blockIdx.x;
    const int ts = (blockIdx.y & 31) * 64;
    const int td = (blockIdx.y >> 5) * 64;
    const int sl = threadIdx.x & 63, dl = threadIdx.x >> 6;
    #pragma unroll
    for (int i = 0; i < 16; ++i)
        tile[dl + 4 * i][sl] = p2[((size_t)b * ND2 + td + dl + 4 * i) * NS + ts + sl];
    __syncthreads();
    const int dl2 = threadIdx.x & 63, sl2 = threadIdx.x >> 6;
    #pragma unroll
    for (int i = 0; i < 16; ++i)
        p2t[((size_t)b * NS + ts + sl2 + 4 * i) * ND2 + td + dl2] =
            (__bf16)tile[dl2][sl2 + 4 * i];
}

// ---------------------------------------------------------------------------
// Kernel 2b: transpose points1 [b][c][n] fp32 -> Xc[b*N+n][0:128] bf16.
// 64c x 64n LDS tile; reads coalesced along n; writes 2x bf16x8 per thread.
// grid (NB, 128 n-tiles x 2 c-tiles).
// ---------------------------------------------------------------------------
__global__ __launch_bounds__(256) void transpose_p1_kernel(
    const float* __restrict__ p1, __bf16* __restrict__ Xc)
{
    __shared__ float tile[64][65];
    const int b  = blockIdx.x;
    const int tn = (blockIdx.y & 127) * 64;
    const int tc = (blockIdx.y >> 7) * 64;
    const int sl = threadIdx.x & 63, dl = threadIdx.x >> 6;
    #pragma unroll
    for (int i = 0; i < 16; ++i)
        tile[dl + 4 * i][sl] = p1[((size_t)b * ND1 + tc + dl + 4 * i) * NPT + tn + sl];
    __syncthreads();
    // thread t: row n_local = t>>2, 16-channel chunk c16 = t&3
    const int n_local = threadIdx.x >> 2, c16 = threadIdx.x & 3;
    __bf16* dst = Xc + ((size_t)b * NPT + tn + n_local) * NIN + tc + c16 * 16;
    bf16x8 v0, v1;
    #pragma unroll
    for (int k = 0; k < 8; ++k) {
        v0[k] = (__bf16)tile[c16 * 16 + k][n_local];
        v1[k] = (__bf16)tile[c16 * 16 + 8 + k][n_local];
    }
    *(bf16x8*)dst = v0;
    *(bf16x8*)(dst + 8) = v1;
}

// ---------------------------------------------------------------------------
// Kernel 3: interp gather -> Xc[n][128:384]. Pure gather now (p1 half is
// written by transpose_p1).
// ---------------------------------------------------------------------------
__global__ __launch_bounds__(256) void build_xc_kernel(
    const __bf16* __restrict__ p2t,
    const int* __restrict__ idx3, const float* __restrict__ wgt3,
    __bf16* __restrict__ Xc)
{
    const int b = blockIdx.x;
    const int n = blockIdx.y * 256 + threadIdx.x;
    const size_t base3 = ((size_t)b * NPT + n) * 3;
    const int i0 = idx3[base3], i1 = idx3[base3 + 1], i2 = idx3[base3 + 2];
    const float w0 = wgt3[base3], w1 = wgt3[base3 + 1], w2 = wgt3[base3 + 2];

    __bf16* dst = Xc + ((size_t)b * NPT + n) * NIN;
    const __bf16* r0 = p2t + ((size_t)b * NS + i0) * ND2;
    const __bf16* r1 = p2t + ((size_t)b * NS + i1) * ND2;
    const __bf16* r2 = p2t + ((size_t)b * NS + i2) * ND2;
    #pragma unroll 2
    for (int d0 = 0; d0 < ND2; d0 += 8) {
        bf16x8 a = *(const bf16x8*)(r0 + d0);
        bf16x8 c = *(const bf16x8*)(r1 + d0);
        bf16x8 e = *(const bf16x8*)(r2 + d0);
        bf16x8 v;
        #pragma unroll
        for (int j = 0; j < 8; ++j)
            v[j] = (__bf16)(w0 * (float)a[j] + w1 * (float)c[j] + w2 * (float)e[j]);
        *(bf16x8*)(dst + ND1 + d0) = v;
    }
}

// ---------------------------------------------------------------------------
// Kernel 4: convert weights to bf16 [o][k]
// ---------------------------------------------------------------------------
__global__ __launch_bounds__(256) void convert_w_kernel(
    const float* __restrict__ w0, const float* __restrict__ w1,
    __bf16* __restrict__ Wb0, __bf16* __restrict__ Wb1)
{
    const int t = blockIdx.x * 256 + threadIdx.x;
    if (t < NC0 * NIN) Wb0[t] = (__bf16)w0[t];
    if (t < NC1 * NC0) Wb1[t] = (__bf16)w1[t];
}

// ---------------------------------------------------------------------------
// Kernel 5: GEMM0 via 16x16x32 bf16 MFMA, LDS-free. 8 waves (4o x 2n),
// tile 256o x 128n, K=384. Writes y0[n][o] bf16. Bias skipped (BN cancels).
// ---------------------------------------------------------------------------
__global__ __launch_bounds__(512, 4) void gemm0_mfma(
    const __bf16* __restrict__ Wb, const __bf16* __restrict__ Xc,
    __bf16* __restrict__ y0, float* __restrict__ sums, float* __restrict__ sumsq)
{
    __shared__ float red[2][NC0][2];
    const int tid = threadIdx.x;
    const int l = tid & 63, w = tid >> 6;
    const int g = l >> 4, lm = l & 15;
    const int ow = w >> 1, nw = w & 1;
    const int o_base = ow * 64;
    const int n_base = blockIdx.x * 128 + nw * 64;

    f32x4 acc[4][4] = {};

    for (int k0 = 0; k0 < NIN; k0 += 32) {
        const int kk = k0 + g * 8;
        bf16x8 af[4], bfr[4];
        #pragma unroll
        for (int m = 0; m < 4; ++m)
            af[m] = *(const bf16x8*)&Wb[(size_t)(o_base + m * 16 + lm) * NIN + kk];
        #pragma unroll
        for (int r = 0; r < 4; ++r)
            bfr[r] = *(const bf16x8*)&Xc[(size_t)(n_base + r * 16 + lm) * NIN + kk];
        #pragma unroll
        for (int m = 0; m < 4; ++m)
            #pragma unroll
            for (int r = 0; r < 4; ++r)
                acc[m][r] = __builtin_amdgcn_mfma_f32_16x16x32_bf16(af[m], bfr[r], acc[m][r], 0, 0, 0);
    }

    #pragma unroll
    for (int m = 0; m < 4; ++m) {
        float s[4] = {0.f, 0.f, 0.f, 0.f}, q[4] = {0.f, 0.f, 0.f, 0.f};
        #pragma unroll
        for (int r = 0; r < 4; ++r) {
            const int n = n_base + r * 16 + lm;
            bf16x4 pk;
            #pragma unroll
            for (int j = 0; j < 4; ++j) {
                float v = acc[m][r][j];
                pk[j] = (__bf16)v;
                s[j] += v; q[j] += v * v;
            }
            *(bf16x4*)&y0[(size_t)n * NC0 + o_base + m * 16 + g * 4] = pk;
        }
        #pragma unroll
        for (int j = 0; j < 4; ++j) {
            #pragma unroll
            for (int st = 1; st < 16; st <<= 1) {
                s[j] += __shfl_xor(s[j], st);
                q[j] += __shfl_xor(q[j], st);
            }
        }
        if (lm == 0) {
            #pragma unroll
            for (int j = 0; j < 4; ++j) {
                red[0][o_base + m * 16 + g * 4 + j][nw] = s[j];
                red[1][o_base + m * 16 + g * 4 + j][nw] = q[j];
            }
        }
    }
    __syncthreads();
    if (tid < NC0) {
        atomicAdd(&sums[tid],  red[0][tid][0] + red[0][tid][1]);
        atomicAdd(&sumsq[tid], red[1][tid][0] + red[1][tid][1]);
    }
}

// ---------------------------------------------------------------------------
// Kernel 6: finalize BN stats -> scale/shift
// ---------------------------------------------------------------------------
__global__ void stats_kernel(
    const float* __restrict__ sums, const float* __restrict__ sumsq,
    const float* __restrict__ g, const float* __restrict__ be,
    float* __restrict__ scale, float* __restrict__ shift, int C)
{
    int c = blockIdx.x * blockDim.x + threadIdx.x;
    if (c < C) {
        const float invN = 1.0f / (float)NBN;
        float mean = sums[c] * invN;
        float var  = sumsq[c] * invN - mean * mean;
        float sc   = g[c] * rsqrtf(var + 1e-5f);
        scale[c] = sc;
        shift[c] = be[c] - mean * sc;
    }
}

// ---------------------------------------------------------------------------
// Kernel 7: GEMM1. B = relu(BN0(y0)) in-register. Writes y1[o][bn] bf16.
// ---------------------------------------------------------------------------
__global__ __launch_bounds__(512, 4) void gemm1_mfma(
    const __bf16* __restrict__ Wb, const __bf16* __restrict__ y0,
    const float* __restrict__ scale0, const float* __restrict__ shift0,
    __bf16* __restrict__ y1, float* __restrict__ sums, float* __restrict__ sumsq)
{
    __shared__ float red[2][NC1][4];
    const int tid = threadIdx.x;
    const int l = tid & 63, w = tid >> 6;
    const int g = l >> 4, lm = l & 15;
    const int ow = w >> 2, nw = w & 3;
    const int o_base = ow * 64;
    const int n_base = blockIdx.x * 128 + nw * 32;

    f32x4 acc[4][2] = {};

    for (int k0 = 0; k0 < NC0; k0 += 32) {
        const int kk = k0 + g * 8;
        f32x4 sc0 = *(const f32x4*)&scale0[kk];
        f32x4 sc1 = *(const f32x4*)&scale0[kk + 4];
        f32x4 sh0 = *(const f32x4*)&shift0[kk];
        f32x4 sh1 = *(const f32x4*)&shift0[kk + 4];
        bf16x8 af[4], bfr[2];
        #pragma unroll
        for (int m = 0; m < 4; ++m)
            af[m] = *(const bf16x8*)&Wb[(size_t)(o_base + m * 16 + lm) * NC0 + kk];
        #pragma unroll
        for (int r = 0; r < 2; ++r) {
            bf16x8 raw = *(const bf16x8*)&y0[(size_t)(n_base + r * 16 + lm) * NC0 + kk];
            bf16x8 bb;
            #pragma unroll
            for (int j = 0; j < 4; ++j) {
                bb[j]     = (__bf16)fmaxf((float)raw[j]     * sc0[j] + sh0[j], 0.f);
                bb[j + 4] = (__bf16)fmaxf((float)raw[j + 4] * sc1[j] + sh1[j], 0.f);
            }
            bfr[r] = bb;
        }
        #pragma unroll
        for (int m = 0; m < 4; ++m)
            #pragma unroll
            for (int r = 0; r < 2; ++r)
                acc[m][r] = __builtin_amdgcn_mfma_f32_16x16x32_bf16(af[m], bfr[r], acc[m][r], 0, 0, 0);
    }

    #pragma unroll
    for (int m = 0; m < 4; ++m) {
        float s[4] = {0.f, 0.f, 0.f, 0.f}, q[4] = {0.f, 0.f, 0.f, 0.f};
        #pragma unroll
        for (int r = 0; r < 2; ++r) {
            const int n = n_base + r * 16 + lm;
            #pragma unroll
            for (int j = 0; j < 4; ++j) {
                float v = acc[m][r][j];
                y1[(size_t)(o_base + m * 16 + g * 4 + j) * NBN + n] = (__bf16)v;
                s[j] += v; q[j] += v * v;
            }
        }
        #pragma unroll
        for (int j = 0; j < 4; ++j) {
            #pragma unroll
            for (int st = 1; st < 16; st <<= 1) {
                s[j] += __shfl_xor(s[j], st);
                q[j] += __shfl_xor(q[j], st);
            }
        }
        if (lm == 0) {
            #pragma unroll
            for (int j = 0; j < 4; ++j) {
                red[0][o_base + m * 16 + g * 4 + j][nw] = s[j];
                red[1][o_base + m * 16 + g * 4 + j][nw] = q[j];
            }
        }
    }
    __syncthreads();
    if (tid < NC1) {
        atomicAdd(&sums[tid],  red[0][tid][0] + red[0][tid][1] + red[0][tid][2] + red[0][tid][3]);
        atomicAdd(&sumsq[tid], red[1][tid][0] + red[1][tid][1] + red[1][tid][2] + red[1][tid][3]);
    }
}

// ---------------------------------------------------------------------------
// Kernel 8: apply BN1 + ReLU; y1 bf16 [o][b*N+n] -> out fp32 [b][o][n]
// ---------------------------------------------------------------------------
__global__ __launch_bounds__(256) void bnout_kernel(
    const __bf16* __restrict__ y1, const float* __restrict__ scale1,
    const float* __restrict__ shift1, float* __restrict__ out)
{
    const size_t t = (size_t)blockIdx.x * 256 + threadIdx.x;
    const size_t e = t * 8;
    const int n = (int)(e & (NPT - 1));
    const int o = (int)((e >> 13) & (NC1 - 1));
    const int b = (int)(e >> 20);
    bf16x8 v = *(const bf16x8*)&y1[(size_t)o * NBN + (size_t)b * NPT + n];
    const float s = scale1[o], sh = shift1[o];
    f32x4 r0, r1;
    #pragma unroll
    for (int j = 0; j < 4; ++j) {
        r0[j] = fmaxf((float)v[j]     * s + sh, 0.f);
        r1[j] = fmaxf((float)v[j + 4] * s + sh, 0.f);
    }
    *(f32x4*)&out[e]     = r0;
    *(f32x4*)&out[e + 4] = r1;
}

// ---------------------------------------------------------------------------
extern "C" void kernel_launch(void* const* d_in, const int* in_sizes, int n_in,
                              void* d_out, int out_size, void* d_ws, size_t ws_size,
                              hipStream_t stream)
{
    const float* xyz1    = (const float*)d_in[0];
    const float* xyz2    = (const float*)d_in[1];
    const float* points1 = (const float*)d_in[2];
    const float* points2 = (const float*)d_in[3];
    const float* w0  = (const float*)d_in[4];
    const float* g0  = (const float*)d_in[6];
    const float* be0 = (const float*)d_in[7];
    const float* w1  = (const float*)d_in[8];
    const float* g1  = (const float*)d_in[10];
    const float* be1 = (const float*)d_in[11];

    char* ws = (char*)d_ws;
    size_t off = 0;
    int*    idx3 = (int*)(ws + off);    off += (size_t)NBN * 3 * 4;        // 768 KB
    float*  wgt3 = (float*)(ws + off);  off += (size_t)NBN * 3 * 4;        // 768 KB
    __bf16* Xc   = (__bf16*)(ws + off); off += (size_t)NBN * NIN * 2;      // 50.3 MB
    __bf16* y0   = (__bf16*)(ws + off); off += (size_t)NBN * NC0 * 2;      // 33.6 MB
    __bf16* y1   = (__bf16*)(ws + off); off += (size_t)NC1 * NBN * 2;      // 16.8 MB
    __bf16* p2t  = (__bf16*)(ws + off); off += (size_t)NB * NS * ND2 * 2;  // 8.4 MB
    __bf16* Wb0  = (__bf16*)(ws + off); off += (size_t)NC0 * NIN * 2;      // 192 KB
    __bf16* Wb1  = (__bf16*)(ws + off); off += (size_t)NC1 * NC0 * 2;      // 64 KB
    float*  stats = (float*)(ws + off);
    float* sums0  = stats;        float* sumsq0 = stats + 256;
    float* sums1  = stats + 512;  float* sumsq1 = stats + 640;
    float* scale0 = stats + 768;  float* shift0 = stats + 1024;
    float* scale1 = stats + 1280; float* shift1 = stats + 1408;

    hipMemsetAsync(stats, 0, 768 * 4, stream);  // zero sum accumulators

    convert_w_kernel   <<<dim3(NC0 * NIN / 256), 256, 0, stream>>>(w0, w1, Wb0, Wb1);
    transpose_p2_kernel<<<dim3(NB, 128), 256, 0, stream>>>(points2, p2t);
    transpose_p1_kernel<<<dim3(NB, 256), 256, 0, stream>>>(points1, Xc);
    knn_kernel         <<<dim3(NB, 128), 256, 0, stream>>>(xyz1, xyz2, idx3, wgt3);
    build_xc_kernel    <<<dim3(NB, NPT / 256), 256, 0, stream>>>(p2t, idx3, wgt3, Xc);
    gemm0_mfma         <<<dim3(NBN / 128), 512, 0, stream>>>(Wb0, Xc, y0, sums0, sumsq0);
    stats_kernel       <<<1, 256, 0, stream>>>(sums0, sumsq0, g0, be0, scale0, shift0, NC0);
    gemm1_mfma         <<<dim3(NBN / 128), 512, 0, stream>>>(Wb1, y0, scale0, shift0, y1, sums1, sumsq1);
    stats_kernel       <<<1, 128, 0, stream>>>(sums1, sumsq1, g1, be1, scale1, shift1, NC1);
    bnout_kernel       <<<dim3(NBN * NC1 / 8 / 256), 256, 0, stream>>>(y1, scale1, shift1, (float*)d_out);
}

// Round 5
// 328.859 us; speedup vs baseline: 1.0406x; 1.0406x over previous
//
#include <hip/hip_runtime.h>

// Problem constants
#define NB   8        // batch
#define NPT  8192     // N query points
#define NS   2048     // S source points
#define ND1  128      // points1 channels
#define ND2  256      // points2 channels
#define NIN  384      // concat channels
#define NC0  256      // MLP[0]
#define NC1  128      // MLP[1]
#define NBN  (NB*NPT) // 65536 total columns

typedef __bf16 bf16x8 __attribute__((ext_vector_type(8)));
typedef __bf16 bf16x4 __attribute__((ext_vector_type(4)));
typedef float  f32x4  __attribute__((ext_vector_type(4)));

// XOR swizzle for the gemm0 B-tile: spreads stride-768B row reads across
// 8 distinct 16B slots per 128B window. MUST be applied on every LDS write
// AND read of Bs (both-sides-or-neither).
#define SWZ(n, off) ((off) ^ (((n) & 7) << 4))

// ---------------------------------------------------------------------------
// Kernel 1: 3-NN + inverse-distance weights. (round-3 structure: 1 query per
// thread, part = tid>>6 -> wave-uniform broadcast pts[s] read, 4 parts x 512
// candidates; branchless top-3.) Distance key uses precomputed -2p1 so it is
// 3 fma per candidate; |p1|^2 re-added at the end (monotonic shift).
// ---------------------------------------------------------------------------
__global__ __launch_bounds__(256) void knn_kernel(
    const float* __restrict__ xyz1, const float* __restrict__ xyz2,
    int* __restrict__ idx3, float* __restrict__ wgt3)
{
    __shared__ float4 pts[NS];      // 32 KB
    __shared__ float md[64][4][3];
    __shared__ int   mi[64][4][3];

    const int b  = blockIdx.x;
    const int qt = blockIdx.y;
    const float* x2 = xyz2 + (size_t)b * 3 * NS;
    for (int s = threadIdx.x; s < NS; s += 256) {
        float x = x2[s], y = x2[NS + s], z = x2[2 * NS + s];
        pts[s] = make_float4(x, y, z, x * x + y * y + z * z);
    }
    __syncthreads();

    const int q    = threadIdx.x & 63;
    const int part = threadIdx.x >> 6;      // wave-uniform
    const int n    = qt * 64 + q;
    const float* x1 = xyz1 + (size_t)b * 3 * NPT;
    const float px = x1[n], py = x1[NPT + n], pz = x1[2 * NPT + n];
    const float qx = -2.f * px, qy = -2.f * py, qz = -2.f * pz;

    float d0 = 3e38f, d1 = 3e38f, d2 = 3e38f;
    int   i0 = 0, i1 = 0, i2 = 0;
    const int sbeg = part * (NS / 4);
    #pragma unroll 2
    for (int s = sbeg; s < sbeg + NS / 4; ++s) {
        float4 p = pts[s];
        float d = fmaf(qx, p.x, fmaf(qy, p.y, fmaf(qz, p.z, p.w)));
        bool c0 = d < d0, c1 = d < d1, c2 = d < d2;
        i2 = c1 ? i1 : (c2 ? s : i2);
        i1 = c0 ? i0 : (c1 ? s : i1);
        i0 = c0 ? s  : i0;
        d2 = fminf(fmaxf(d, d1), d2);       // med3(d1,d2,d)
        d1 = fminf(fmaxf(d, d0), d1);       // med3(d0,d1,d)
        d0 = fminf(d, d0);
    }
    md[q][part][0] = d0; md[q][part][1] = d1; md[q][part][2] = d2;
    mi[q][part][0] = i0; mi[q][part][1] = i1; mi[q][part][2] = i2;
    __syncthreads();

    if (threadIdx.x < 64) {
        // 4-way merge of sorted triples; ascending part + strict < keeps
        // lowest s on ties (parts are s-ordered) = top_k tie-break.
        int hp[4] = {0, 0, 0, 0};
        float rd[3]; int ri[3];
        #pragma unroll
        for (int k = 0; k < 3; ++k) {
            float best = 3.0e38f; int bl = 0;
            #pragma unroll
            for (int l = 0; l < 4; ++l) {
                float dv = md[q][l][hp[l]];
                if (dv < best) { best = dv; bl = l; }
            }
            rd[k] = best; ri[k] = mi[q][bl][hp[bl]]; hp[bl]++;
        }
        const float p1sq = px * px + py * py + pz * pz;
        float r0 = 1.0f / (rd[0] + p1sq + 1e-8f);
        float r1 = 1.0f / (rd[1] + p1sq + 1e-8f);
        float r2 = 1.0f / (rd[2] + p1sq + 1e-8f);
        float inv = 1.0f / (r0 + r1 + r2);
        size_t base = ((size_t)b * NPT + n) * 3;
        idx3[base] = ri[0]; idx3[base + 1] = ri[1]; idx3[base + 2] = ri[2];
        wgt3[base] = r0 * inv; wgt3[base + 1] = r1 * inv; wgt3[base + 2] = r2 * inv;
    }
}

// ---------------------------------------------------------------------------
// Kernel 2: transpose points2 [b][d][s] fp32 -> p2t [b][s][d] bf16.
// ---------------------------------------------------------------------------
__global__ __launch_bounds__(256) void transpose_p2_kernel(
    const float* __restrict__ p2, __bf16* __restrict__ p2t)
{
    __shared__ float tile[64][65];
    const int b  = blockIdx.x;
    const int ts = (blockIdx.y & 31) * 64;
    const int td = (blockIdx.y >> 5) * 64;
    const int sl = threadIdx.x & 63, dl = threadIdx.x >> 6;
    #pragma unroll
    for (int i = 0; i < 16; ++i)
        tile[dl + 4 * i][sl] = p2[((size_t)b * ND2 + td + dl + 4 * i) * NS + ts + sl];
    __syncthreads();
    const int dl2 = threadIdx.x & 63, sl2 = threadIdx.x >> 6;
    #pragma unroll
    for (int i = 0; i < 16; ++i)
        p2t[((size_t)b * NS + ts + sl2 + 4 * i) * ND2 + td + dl2] =
            (__bf16)tile[dl2][sl2 + 4 * i];
}

// ---------------------------------------------------------------------------
// Kernel 2b: transpose points1 [b][c][n] fp32 -> XcP1[b*N+n][0:128] bf16.
// ---------------------------------------------------------------------------
__global__ __launch_bounds__(256) void transpose_p1_kernel(
    const float* __restrict__ p1, __bf16* __restrict__ XcP1)
{
    __shared__ float tile[64][65];
    const int b  = blockIdx.x;
    const int tn = (blockIdx.y & 127) * 64;
    const int tc = (blockIdx.y >> 7) * 64;
    const int sl = threadIdx.x & 63, dl = threadIdx.x >> 6;
    #pragma unroll
    for (int i = 0; i < 16; ++i)
        tile[dl + 4 * i][sl] = p1[((size_t)b * ND1 + tc + dl + 4 * i) * NPT + tn + sl];
    __syncthreads();
    const int n_local = threadIdx.x >> 2, c16 = threadIdx.x & 3;
    __bf16* dst = XcP1 + ((size_t)b * NPT + tn + n_local) * ND1 + tc + c16 * 16;
    bf16x8 v0, v1;
    #pragma unroll
    for (int k = 0; k < 8; ++k) {
        v0[k] = (__bf16)tile[c16 * 16 + k][n_local];
        v1[k] = (__bf16)tile[c16 * 16 + 8 + k][n_local];
    }
    *(bf16x8*)dst = v0;
    *(bf16x8*)(dst + 8) = v1;
}

// ---------------------------------------------------------------------------
// Kernel 3: convert weights to bf16 [o][k]
// ---------------------------------------------------------------------------
__global__ __launch_bounds__(256) void convert_w_kernel(
    const float* __restrict__ w0, const float* __restrict__ w1,
    __bf16* __restrict__ Wb0, __bf16* __restrict__ Wb1)
{
    const int t = blockIdx.x * 256 + threadIdx.x;
    if (t < NC0 * NIN) Wb0[t] = (__bf16)w0[t];
    if (t < NC1 * NC0) Wb1[t] = (__bf16)w1[t];
}

// ---------------------------------------------------------------------------
// Kernel 4: GEMM0 with FUSED interpolation. Block = 512 thr (8 waves,
// 4o x 2n), tile o=256 (all) x n=64, K=384. B-tile staged in LDS:
//   Bs[n][0:128]   <- XcP1 (coalesced copy)
//   Bs[n][128:384] <- gather 3 p2t rows + weighted blend (the interp, fused)
// XOR-swizzled LDS (SWZ on both write and read). A (weights) from global.
// Eliminates the Xc interp buffer (67 MB HBM round trip) and build_xc pass.
// Writes y0[n][o] bf16 + per-channel sum/sumsq atomics. Bias dropped (BN).
// ---------------------------------------------------------------------------
__global__ __launch_bounds__(512, 4) void gemm0_fused(
    const __bf16* __restrict__ Wb, const __bf16* __restrict__ XcP1,
    const __bf16* __restrict__ p2t,
    const int* __restrict__ idx3, const float* __restrict__ wgt3,
    __bf16* __restrict__ y0, float* __restrict__ sums, float* __restrict__ sumsq)
{
    __shared__ char BsRaw[64 * NIN * 2];   // 48 KB, [n][384] bf16 swizzled
    __shared__ float red[2][NC0][2];       // 4 KB
    char* lds = BsRaw;

    const int tid = threadIdx.x;
    const int bn0 = blockIdx.x * 64;       // global column base
    const int b   = bn0 / NPT;

    // ---- stage S1: p1 half (k = 0..127), coalesced from XcP1 ----
    #pragma unroll
    for (int i = 0; i < 2; ++i) {
        const int id = tid + i * 512;      // 0..1023
        const int n  = id >> 4;            // 0..63
        const int c8 = (id & 15) * 8;      // 0..120
        bf16x8 v = *(const bf16x8*)&XcP1[(size_t)(bn0 + n) * ND1 + c8];
        *(bf16x8*)(lds + n * (NIN * 2) + SWZ(n, c8 * 2)) = v;
    }

    // ---- stage S2: interp half (k = 128..383), fused gather+blend ----
    {
        const int ng   = tid >> 3;         // 0..63
        const int part = tid & 7;          // 0..7
        const size_t base3 = (size_t)(bn0 + ng) * 3;
        const int i0 = idx3[base3], i1 = idx3[base3 + 1], i2 = idx3[base3 + 2];
        const float w0 = wgt3[base3], w1 = wgt3[base3 + 1], w2 = wgt3[base3 + 2];
        const __bf16* r0 = p2t + ((size_t)b * NS + i0) * ND2;
        const __bf16* r1 = p2t + ((size_t)b * NS + i1) * ND2;
        const __bf16* r2 = p2t + ((size_t)b * NS + i2) * ND2;
        #pragma unroll
        for (int i = 0; i < 4; ++i) {
            const int d0 = part * 32 + i * 8;   // 0..255
            bf16x8 a = *(const bf16x8*)(r0 + d0);
            bf16x8 c = *(const bf16x8*)(r1 + d0);
            bf16x8 e = *(const bf16x8*)(r2 + d0);
            bf16x8 v;
            #pragma unroll
            for (int j = 0; j < 8; ++j)
                v[j] = (__bf16)(w0 * (float)a[j] + w1 * (float)c[j] + w2 * (float)e[j]);
            *(bf16x8*)(lds + ng * (NIN * 2) + SWZ(ng, (ND1 + d0) * 2)) = v;
        }
    }
    __syncthreads();

    // ---- MFMA main loop: A from global, B from swizzled LDS ----
    const int l = tid & 63, w = tid >> 6;
    const int g = l >> 4, lm = l & 15;
    const int ow = w >> 1, nw = w & 1;     // 4 o-waves x 2 n-waves
    const int o_base = ow * 64;

    f32x4 acc[4][2] = {};

    for (int k0 = 0; k0 < NIN; k0 += 32) {
        const int kk = k0 + g * 8;
        bf16x8 af[4], bfr[2];
        #pragma unroll
        for (int m = 0; m < 4; ++m)
            af[m] = *(const bf16x8*)&Wb[(size_t)(o_base + m * 16 + lm) * NIN + kk];
        #pragma unroll
        for (int r = 0; r < 2; ++r) {
            const int n_lds = nw * 32 + r * 16 + lm;
            bfr[r] = *(const bf16x8*)(lds + n_lds * (NIN * 2) + SWZ(n_lds, kk * 2));
        }
        #pragma unroll
        for (int m = 0; m < 4; ++m)
            #pragma unroll
            for (int r = 0; r < 2; ++r)
                acc[m][r] = __builtin_amdgcn_mfma_f32_16x16x32_bf16(af[m], bfr[r], acc[m][r], 0, 0, 0);
    }

    // ---- epilogue: y0[n][o] bf16 + stats ----
    #pragma unroll
    for (int m = 0; m < 4; ++m) {
        float s[4] = {0.f, 0.f, 0.f, 0.f}, q[4] = {0.f, 0.f, 0.f, 0.f};
        #pragma unroll
        for (int r = 0; r < 2; ++r) {
            const int n = nw * 32 + r * 16 + lm;
            bf16x4 pk;
            #pragma unroll
            for (int j = 0; j < 4; ++j) {
                float v = acc[m][r][j];
                pk[j] = (__bf16)v;
                s[j] += v; q[j] += v * v;
            }
            *(bf16x4*)&y0[(size_t)(bn0 + n) * NC0 + o_base + m * 16 + g * 4] = pk;
        }
        #pragma unroll
        for (int j = 0; j < 4; ++j) {
            #pragma unroll
            for (int st = 1; st < 16; st <<= 1) {
                s[j] += __shfl_xor(s[j], st);
                q[j] += __shfl_xor(q[j], st);
            }
        }
        if (lm == 0) {
            #pragma unroll
            for (int j = 0; j < 4; ++j) {
                red[0][o_base + m * 16 + g * 4 + j][nw] = s[j];
                red[1][o_base + m * 16 + g * 4 + j][nw] = q[j];
            }
        }
    }
    __syncthreads();
    if (tid < NC0) {
        atomicAdd(&sums[tid],  red[0][tid][0] + red[0][tid][1]);
        atomicAdd(&sumsq[tid], red[1][tid][0] + red[1][tid][1]);
    }
}

// ---------------------------------------------------------------------------
// Kernel 5: finalize BN stats -> scale/shift
// ---------------------------------------------------------------------------
__global__ void stats_kernel(
    const float* __restrict__ sums, const float* __restrict__ sumsq,
    const float* __restrict__ g, const float* __restrict__ be,
    float* __restrict__ scale, float* __restrict__ shift, int C)
{
    int c = blockIdx.x * blockDim.x + threadIdx.x;
    if (c < C) {
        const float invN = 1.0f / (float)NBN;
        float mean = sums[c] * invN;
        float var  = sumsq[c] * invN - mean * mean;
        float sc   = g[c] * rsqrtf(var + 1e-5f);
        scale[c] = sc;
        shift[c] = be[c] - mean * sc;
    }
}

// ---------------------------------------------------------------------------
// Kernel 6: GEMM1. B = relu(BN0(y0)) in-register. Writes y1[o][bn] bf16.
// ---------------------------------------------------------------------------
__global__ __launch_bounds__(512, 4) void gemm1_mfma(
    const __bf16* __restrict__ Wb, const __bf16* __restrict__ y0,
    const float* __restrict__ scale0, const float* __restrict__ shift0,
    __bf16* __restrict__ y1, float* __restrict__ sums, float* __restrict__ sumsq)
{
    __shared__ float red[2][NC1][4];
    const int tid = threadIdx.x;
    const int l = tid & 63, w = tid >> 6;
    const int g = l >> 4, lm = l & 15;
    const int ow = w >> 2, nw = w & 3;
    const int o_base = ow * 64;
    const int n_base = blockIdx.x * 128 + nw * 32;

    f32x4 acc[4][2] = {};

    for (int k0 = 0; k0 < NC0; k0 += 32) {
        const int kk = k0 + g * 8;
        f32x4 sc0 = *(const f32x4*)&scale0[kk];
        f32x4 sc1 = *(const f32x4*)&scale0[kk + 4];
        f32x4 sh0 = *(const f32x4*)&shift0[kk];
        f32x4 sh1 = *(const f32x4*)&shift0[kk + 4];
        bf16x8 af[4], bfr[2];
        #pragma unroll
        for (int m = 0; m < 4; ++m)
            af[m] = *(const bf16x8*)&Wb[(size_t)(o_base + m * 16 + lm) * NC0 + kk];
        #pragma unroll
        for (int r = 0; r < 2; ++r) {
            bf16x8 raw = *(const bf16x8*)&y0[(size_t)(n_base + r * 16 + lm) * NC0 + kk];
            bf16x8 bb;
            #pragma unroll
            for (int j = 0; j < 4; ++j) {
                bb[j]     = (__bf16)fmaxf((float)raw[j]     * sc0[j] + sh0[j], 0.f);
                bb[j + 4] = (__bf16)fmaxf((float)raw[j + 4] * sc1[j] + sh1[j], 0.f);
            }
            bfr[r] = bb;
        }
        #pragma unroll
        for (int m = 0; m < 4; ++m)
            #pragma unroll
            for (int r = 0; r < 2; ++r)
                acc[m][r] = __builtin_amdgcn_mfma_f32_16x16x32_bf16(af[m], bfr[r], acc[m][r], 0, 0, 0);
    }

    #pragma unroll
    for (int m = 0; m < 4; ++m) {
        float s[4] = {0.f, 0.f, 0.f, 0.f}, q[4] = {0.f, 0.f, 0.f, 0.f};
        #pragma unroll
        for (int r = 0; r < 2; ++r) {
            const int n = n_base + r * 16 + lm;
            #pragma unroll
            for (int j = 0; j < 4; ++j) {
                float v = acc[m][r][j];
                y1[(size_t)(o_base + m * 16 + g * 4 + j) * NBN + n] = (__bf16)v;
                s[j] += v; q[j] += v * v;
            }
        }
        #pragma unroll
        for (int j = 0; j < 4; ++j) {
            #pragma unroll
            for (int st = 1; st < 16; st <<= 1) {
                s[j] += __shfl_xor(s[j], st);
                q[j] += __shfl_xor(q[j], st);
            }
        }
        if (lm == 0) {
            #pragma unroll
            for (int j = 0; j < 4; ++j) {
                red[0][o_base + m * 16 + g * 4 + j][nw] = s[j];
                red[1][o_base + m * 16 + g * 4 + j][nw] = q[j];
            }
        }
    }
    __syncthreads();
    if (tid < NC1) {
        atomicAdd(&sums[tid],  red[0][tid][0] + red[0][tid][1] + red[0][tid][2] + red[0][tid][3]);
        atomicAdd(&sumsq[tid], red[1][tid][0] + red[1][tid][1] + red[1][tid][2] + red[1][tid][3]);
    }
}

// ---------------------------------------------------------------------------
// Kernel 7: apply BN1 + ReLU; y1 bf16 [o][b*N+n] -> out fp32 [b][o][n]
// ---------------------------------------------------------------------------
__global__ __launch_bounds__(256) void bnout_kernel(
    const __bf16* __restrict__ y1, const float* __restrict__ scale1,
    const float* __restrict__ shift1, float* __restrict__ out)
{
    const size_t t = (size_t)blockIdx.x * 256 + threadIdx.x;
    const size_t e = t * 8;
    const int n = (int)(e & (NPT - 1));
    const int o = (int)((e >> 13) & (NC1 - 1));
    const int b = (int)(e >> 20);
    bf16x8 v = *(const bf16x8*)&y1[(size_t)o * NBN + (size_t)b * NPT + n];
    const float s = scale1[o], sh = shift1[o];
    f32x4 r0, r1;
    #pragma unroll
    for (int j = 0; j < 4; ++j) {
        r0[j] = fmaxf((float)v[j]     * s + sh, 0.f);
        r1[j] = fmaxf((float)v[j + 4] * s + sh, 0.f);
    }
    *(f32x4*)&out[e]     = r0;
    *(f32x4*)&out[e + 4] = r1;
}

// ---------------------------------------------------------------------------
extern "C" void kernel_launch(void* const* d_in, const int* in_sizes, int n_in,
                              void* d_out, int out_size, void* d_ws, size_t ws_size,
                              hipStream_t stream)
{
    const float* xyz1    = (const float*)d_in[0];
    const float* xyz2    = (const float*)d_in[1];
    const float* points1 = (const float*)d_in[2];
    const float* points2 = (const float*)d_in[3];
    const float* w0  = (const float*)d_in[4];
    const float* g0  = (const float*)d_in[6];
    const float* be0 = (const float*)d_in[7];
    const float* w1  = (const float*)d_in[8];
    const float* g1  = (const float*)d_in[10];
    const float* be1 = (const float*)d_in[11];

    char* ws = (char*)d_ws;
    size_t off = 0;
    int*    idx3 = (int*)(ws + off);    off += (size_t)NBN * 3 * 4;        // 768 KB
    float*  wgt3 = (float*)(ws + off);  off += (size_t)NBN * 3 * 4;        // 768 KB
    __bf16* XcP1 = (__bf16*)(ws + off); off += (size_t)NBN * ND1 * 2;      // 16.8 MB
    __bf16* y0   = (__bf16*)(ws + off); off += (size_t)NBN * NC0 * 2;      // 33.6 MB
    __bf16* y1   = (__bf16*)(ws + off); off += (size_t)NC1 * NBN * 2;      // 16.8 MB
    __bf16* p2t  = (__bf16*)(ws + off); off += (size_t)NB * NS * ND2 * 2;  // 8.4 MB
    __bf16* Wb0  = (__bf16*)(ws + off); off += (size_t)NC0 * NIN * 2;      // 192 KB
    __bf16* Wb1  = (__bf16*)(ws + off); off += (size_t)NC1 * NC0 * 2;      // 64 KB
    float*  stats = (float*)(ws + off);
    float* sums0  = stats;        float* sumsq0 = stats + 256;
    float* sums1  = stats + 512;  float* sumsq1 = stats + 640;
    float* scale0 = stats + 768;  float* shift0 = stats + 1024;
    float* scale1 = stats + 1280; float* shift1 = stats + 1408;

    hipMemsetAsync(stats, 0, 768 * 4, stream);  // zero sum accumulators

    convert_w_kernel   <<<dim3(NC0 * NIN / 256), 256, 0, stream>>>(w0, w1, Wb0, Wb1);
    transpose_p2_kernel<<<dim3(NB, 128), 256, 0, stream>>>(points2, p2t);
    transpose_p1_kernel<<<dim3(NB, 256), 256, 0, stream>>>(points1, XcP1);
    knn_kernel         <<<dim3(NB, 128), 256, 0, stream>>>(xyz1, xyz2, idx3, wgt3);
    gemm0_fused        <<<dim3(NBN / 64), 512, 0, stream>>>(
        Wb0, XcP1, p2t, idx3, wgt3, y0, sums0, sumsq0);
    stats_kernel       <<<1, 256, 0, stream>>>(sums0, sumsq0, g0, be0, scale0, shift0, NC0);
    gemm1_mfma         <<<dim3(NBN / 128), 512, 0, stream>>>(Wb1, y0, scale0, shift0, y1, sums1, sumsq1);
    stats_kernel       <<<1, 128, 0, stream>>>(sums1, sumsq1, g1, be1, scale1, shift1, NC1);
    bnout_kernel       <<<dim3(NBN * NC1 / 8 / 256), 256, 0, stream>>>(y1, scale1, shift1, (float*)d_out);
}

// Round 8
// 327.945 us; speedup vs baseline: 1.0435x; 1.0028x over previous
//
#include <hip/hip_runtime.h>

// Problem constants
#define NB   8        // batch
#define NPT  8192     // N query points
#define NS   2048     // S source points
#define ND1  128      // points1 channels
#define ND2  256      // points2 channels
#define NIN  384      // concat channels
#define NC0  256      // MLP[0]
#define NC1  128      // MLP[1]
#define NBN  (NB*NPT) // 65536 total columns

typedef __bf16 bf16x8 __attribute__((ext_vector_type(8)));
typedef __bf16 bf16x4 __attribute__((ext_vector_type(4)));
typedef float  f32x4  __attribute__((ext_vector_type(4)));

// XOR swizzle for the gemm0 interp LDS tile ([64][256] bf16, 512B rows):
// applied on BOTH write and read (both-sides-or-neither).
#define SWZ(n, off) ((off) ^ (((n) & 7) << 4))

// ---------------------------------------------------------------------------
// Kernel 1: 3-NN + inverse-distance weights. (known-good round-5 version:
// full-precision float keys + branchless index cndmask — do NOT quantize the
// sort key; truncation corrupts which index wins near-ties, and the gathered
// feature of a wrong neighbor is an O(1) error.)
// 64 queries/block, part = tid>>6 wave-uniform, 4 parts x 512 candidates.
// ---------------------------------------------------------------------------
__global__ __launch_bounds__(256) void knn_kernel(
    const float* __restrict__ xyz1, const float* __restrict__ xyz2,
    int* __restrict__ idx3, float* __restrict__ wgt3)
{
    __shared__ float4 pts[NS];      // 32 KB
    __shared__ float md[64][4][3];
    __shared__ int   mi[64][4][3];

    const int b  = blockIdx.x;
    const int qt = blockIdx.y;
    const float* x2 = xyz2 + (size_t)b * 3 * NS;
    for (int s = threadIdx.x; s < NS; s += 256) {
        float x = x2[s], y = x2[NS + s], z = x2[2 * NS + s];
        pts[s] = make_float4(x, y, z, x * x + y * y + z * z);
    }
    __syncthreads();

    const int q    = threadIdx.x & 63;
    const int part = threadIdx.x >> 6;      // wave-uniform
    const int n    = qt * 64 + q;
    const float* x1 = xyz1 + (size_t)b * 3 * NPT;
    const float px = x1[n], py = x1[NPT + n], pz = x1[2 * NPT + n];
    const float qx = -2.f * px, qy = -2.f * py, qz = -2.f * pz;

    float d0 = 3e38f, d1 = 3e38f, d2 = 3e38f;
    int   i0 = 0, i1 = 0, i2 = 0;
    const int sbeg = part * (NS / 4);
    #pragma unroll 2
    for (int s = sbeg; s < sbeg + NS / 4; ++s) {
        float4 p = pts[s];
        float d = fmaf(qx, p.x, fmaf(qy, p.y, fmaf(qz, p.z, p.w)));
        bool c0 = d < d0, c1 = d < d1, c2 = d < d2;
        i2 = c1 ? i1 : (c2 ? s : i2);
        i1 = c0 ? i0 : (c1 ? s : i1);
        i0 = c0 ? s  : i0;
        d2 = fminf(fmaxf(d, d1), d2);       // med3(d1,d2,d)
        d1 = fminf(fmaxf(d, d0), d1);       // med3(d0,d1,d)
        d0 = fminf(d, d0);
    }
    md[q][part][0] = d0; md[q][part][1] = d1; md[q][part][2] = d2;
    mi[q][part][0] = i0; mi[q][part][1] = i1; mi[q][part][2] = i2;
    __syncthreads();

    if (threadIdx.x < 64) {
        // 4-way merge of sorted triples; ascending part + strict < keeps
        // lowest s on ties (parts are s-ordered) = top_k tie-break.
        int hp[4] = {0, 0, 0, 0};
        float rd[3]; int ri[3];
        #pragma unroll
        for (int k = 0; k < 3; ++k) {
            float best = 3.0e38f; int bl = 0;
            #pragma unroll
            for (int l = 0; l < 4; ++l) {
                float dv = md[q][l][hp[l]];
                if (dv < best) { best = dv; bl = l; }
            }
            rd[k] = best; ri[k] = mi[q][bl][hp[bl]]; hp[bl]++;
        }
        const float p1sq = px * px + py * py + pz * pz;
        float r0 = 1.0f / (rd[0] + p1sq + 1e-8f);
        float r1 = 1.0f / (rd[1] + p1sq + 1e-8f);
        float r2 = 1.0f / (rd[2] + p1sq + 1e-8f);
        float inv = 1.0f / (r0 + r1 + r2);
        size_t base = ((size_t)b * NPT + n) * 3;
        idx3[base] = ri[0]; idx3[base + 1] = ri[1]; idx3[base + 2] = ri[2];
        wgt3[base] = r0 * inv; wgt3[base + 1] = r1 * inv; wgt3[base + 2] = r2 * inv;
    }
}

// ---------------------------------------------------------------------------
// Kernel 2: transpose points2 [b][d][s] fp32 -> p2t [b][s][d] bf16.
// ---------------------------------------------------------------------------
__global__ __launch_bounds__(256) void transpose_p2_kernel(
    const float* __restrict__ p2, __bf16* __restrict__ p2t)
{
    __shared__ float tile[64][65];
    const int b  = blockIdx.x;
    const int ts = (blockIdx.y & 31) * 64;
    const int td = (blockIdx.y >> 5) * 64;
    const int sl = threadIdx.x & 63, dl = threadIdx.x >> 6;
    #pragma unroll
    for (int i = 0; i < 16; ++i)
        tile[dl + 4 * i][sl] = p2[((size_t)b * ND2 + td + dl + 4 * i) * NS + ts + sl];
    __syncthreads();
    const int dl2 = threadIdx.x & 63, sl2 = threadIdx.x >> 6;
    #pragma unroll
    for (int i = 0; i < 16; ++i)
        p2t[((size_t)b * NS + ts + sl2 + 4 * i) * ND2 + td + dl2] =
            (__bf16)tile[dl2][sl2 + 4 * i];
}

// ---------------------------------------------------------------------------
// Kernel 2b: transpose points1 [b][c][n] fp32 -> XcP1[b*N+n][0:128] bf16.
// ---------------------------------------------------------------------------
__global__ __launch_bounds__(256) void transpose_p1_kernel(
    const float* __restrict__ p1, __bf16* __restrict__ XcP1)
{
    __shared__ float tile[64][65];
    const int b  = blockIdx.x;
    const int tn = (blockIdx.y & 127) * 64;
    const int tc = (blockIdx.y >> 7) * 64;
    const int sl = threadIdx.x & 63, dl = threadIdx.x >> 6;
    #pragma unroll
    for (int i = 0; i < 16; ++i)
        tile[dl + 4 * i][sl] = p1[((size_t)b * ND1 + tc + dl + 4 * i) * NPT + tn + sl];
    __syncthreads();
    const int n_local = threadIdx.x >> 2, c16 = threadIdx.x & 3;
    __bf16* dst = XcP1 + ((size_t)b * NPT + tn + n_local) * ND1 + tc + c16 * 16;
    bf16x8 v0, v1;
    #pragma unroll
    for (int k = 0; k < 8; ++k) {
        v0[k] = (__bf16)tile[c16 * 16 + k][n_local];
        v1[k] = (__bf16)tile[c16 * 16 + 8 + k][n_local];
    }
    *(bf16x8*)dst = v0;
    *(bf16x8*)(dst + 8) = v1;
}

// ---------------------------------------------------------------------------
// Kernel 3: convert weights to bf16 [o][k]
// ---------------------------------------------------------------------------
__global__ __launch_bounds__(256) void convert_w_kernel(
    const float* __restrict__ w0, const float* __restrict__ w1,
    __bf16* __restrict__ Wb0, __bf16* __restrict__ Wb1)
{
    const int t = blockIdx.x * 256 + threadIdx.x;
    if (t < NC0 * NIN) Wb0[t] = (__bf16)w0[t];
    if (t < NC1 * NC0) Wb1[t] = (__bf16)w1[t];
}

// ---------------------------------------------------------------------------
// Kernel 4: GEMM0 + fused interp, PIPELINED:
//   A1: issue 6 gather loads -> B1: MFMA k=0..63 (B from XcP1 global)
//   C1: blend+LDS-write; A2: next 6 gathers -> B2: MFMA k=64..127 (global)
//   C2: blend+write -> barrier -> D: MFMA k=128..383 from swizzled LDS.
// ---------------------------------------------------------------------------
__global__ __launch_bounds__(512, 4) void gemm0_fused(
    const __bf16* __restrict__ Wb, const __bf16* __restrict__ XcP1,
    const __bf16* __restrict__ p2t,
    const int* __restrict__ idx3, const float* __restrict__ wgt3,
    __bf16* __restrict__ y0, float* __restrict__ sums, float* __restrict__ sumsq)
{
    __shared__ char Bs[64 * ND2 * 2];      // 32 KB, [n][256] bf16 swizzled
    __shared__ float red[2][NC0][2];       // 4 KB

    const int tid = threadIdx.x;
    const int bn0 = blockIdx.x * 64;
    const int b   = bn0 / NPT;

    // gather setup
    const int ng   = tid >> 3;             // 0..63
    const int part = tid & 7;              // 0..7
    const size_t base3 = (size_t)(bn0 + ng) * 3;
    const int gi0 = idx3[base3], gi1 = idx3[base3 + 1], gi2 = idx3[base3 + 2];
    const float gw0 = wgt3[base3], gw1 = wgt3[base3 + 1], gw2 = wgt3[base3 + 2];
    const __bf16* r0 = p2t + ((size_t)b * NS + gi0) * ND2;
    const __bf16* r1 = p2t + ((size_t)b * NS + gi1) * ND2;
    const __bf16* r2 = p2t + ((size_t)b * NS + gi2) * ND2;

    // MFMA lane mapping
    const int l = tid & 63, w = tid >> 6;
    const int g = l >> 4, lm = l & 15;
    const int ow = w >> 1, nw = w & 1;     // 4 o-waves x 2 n-waves
    const int o_base = ow * 64;

    f32x4 acc[4][2] = {};

    // ---- A1: issue first 6 gathers ----
    bf16x8 rawA0, rawA1, rawA2, rawB0, rawB1, rawB2;
    {
        const int d0 = part * 32;
        rawA0 = *(const bf16x8*)(r0 + d0);     rawA1 = *(const bf16x8*)(r1 + d0);
        rawA2 = *(const bf16x8*)(r2 + d0);
        rawB0 = *(const bf16x8*)(r0 + d0 + 8); rawB1 = *(const bf16x8*)(r1 + d0 + 8);
        rawB2 = *(const bf16x8*)(r2 + d0 + 8);
    }

    // ---- B1: MFMA k = 0..63, B from global XcP1 ----
    #pragma unroll
    for (int k0 = 0; k0 < 64; k0 += 32) {
        const int kk = k0 + g * 8;
        bf16x8 af[4], bfr[2];
        #pragma unroll
        for (int m = 0; m < 4; ++m)
            af[m] = *(const bf16x8*)&Wb[(size_t)(o_base + m * 16 + lm) * NIN + kk];
        #pragma unroll
        for (int r = 0; r < 2; ++r) {
            const int n = nw * 32 + r * 16 + lm;
            bfr[r] = *(const bf16x8*)&XcP1[(size_t)(bn0 + n) * ND1 + kk];
        }
        #pragma unroll
        for (int m = 0; m < 4; ++m)
            #pragma unroll
            for (int r = 0; r < 2; ++r)
                acc[m][r] = __builtin_amdgcn_mfma_f32_16x16x32_bf16(af[m], bfr[r], acc[m][r], 0, 0, 0);
    }

    // ---- C1: blend + LDS write; A2: issue next 6 gathers ----
    {
        bf16x8 v0, v1;
        #pragma unroll
        for (int j = 0; j < 8; ++j) {
            v0[j] = (__bf16)(gw0 * (float)rawA0[j] + gw1 * (float)rawA1[j] + gw2 * (float)rawA2[j]);
            v1[j] = (__bf16)(gw0 * (float)rawB0[j] + gw1 * (float)rawB1[j] + gw2 * (float)rawB2[j]);
        }
        const int d0 = part * 32;
        *(bf16x8*)(Bs + ng * (ND2 * 2) + SWZ(ng, d0 * 2))       = v0;
        *(bf16x8*)(Bs + ng * (ND2 * 2) + SWZ(ng, (d0 + 8) * 2)) = v1;
    }
    {
        const int d0 = part * 32 + 16;
        rawA0 = *(const bf16x8*)(r0 + d0);     rawA1 = *(const bf16x8*)(r1 + d0);
        rawA2 = *(const bf16x8*)(r2 + d0);
        rawB0 = *(const bf16x8*)(r0 + d0 + 8); rawB1 = *(const bf16x8*)(r1 + d0 + 8);
        rawB2 = *(const bf16x8*)(r2 + d0 + 8);
    }

    // ---- B2: MFMA k = 64..127, B from global XcP1 ----
    #pragma unroll
    for (int k0 = 64; k0 < 128; k0 += 32) {
        const int kk = k0 + g * 8;
        bf16x8 af[4], bfr[2];
        #pragma unroll
        for (int m = 0; m < 4; ++m)
            af[m] = *(const bf16x8*)&Wb[(size_t)(o_base + m * 16 + lm) * NIN + kk];
        #pragma unroll
        for (int r = 0; r < 2; ++r) {
            const int n = nw * 32 + r * 16 + lm;
            bfr[r] = *(const bf16x8*)&XcP1[(size_t)(bn0 + n) * ND1 + kk];
        }
        #pragma unroll
        for (int m = 0; m < 4; ++m)
            #pragma unroll
            for (int r = 0; r < 2; ++r)
                acc[m][r] = __builtin_amdgcn_mfma_f32_16x16x32_bf16(af[m], bfr[r], acc[m][r], 0, 0, 0);
    }

    // ---- C2: blend + LDS write ----
    {
        bf16x8 v0, v1;
        #pragma unroll
        for (int j = 0; j < 8; ++j) {
            v0[j] = (__bf16)(gw0 * (float)rawA0[j] + gw1 * (float)rawA1[j] + gw2 * (float)rawA2[j]);
            v1[j] = (__bf16)(gw0 * (float)rawB0[j] + gw1 * (float)rawB1[j] + gw2 * (float)rawB2[j]);
        }
        const int d0 = part * 32 + 16;
        *(bf16x8*)(Bs + ng * (ND2 * 2) + SWZ(ng, d0 * 2))       = v0;
        *(bf16x8*)(Bs + ng * (ND2 * 2) + SWZ(ng, (d0 + 8) * 2)) = v1;
    }
    __syncthreads();

    // ---- D: MFMA k = 128..383 from swizzled LDS ----
    #pragma unroll
    for (int k0 = 128; k0 < NIN; k0 += 32) {
        const int kd = k0 - 128 + g * 8;
        bf16x8 af[4], bfr[2];
        #pragma unroll
        for (int m = 0; m < 4; ++m)
            af[m] = *(const bf16x8*)&Wb[(size_t)(o_base + m * 16 + lm) * NIN + k0 + g * 8];
        #pragma unroll
        for (int r = 0; r < 2; ++r) {
            const int n_lds = nw * 32 + r * 16 + lm;
            bfr[r] = *(const bf16x8*)(Bs + n_lds * (ND2 * 2) + SWZ(n_lds, kd * 2));
        }
        #pragma unroll
        for (int m = 0; m < 4; ++m)
            #pragma unroll
            for (int r = 0; r < 2; ++r)
                acc[m][r] = __builtin_amdgcn_mfma_f32_16x16x32_bf16(af[m], bfr[r], acc[m][r], 0, 0, 0);
    }

    // ---- epilogue: y0[n][o] bf16 + stats ----
    #pragma unroll
    for (int m = 0; m < 4; ++m) {
        float s[4] = {0.f, 0.f, 0.f, 0.f}, q[4] = {0.f, 0.f, 0.f, 0.f};
        #pragma unroll
        for (int r = 0; r < 2; ++r) {
            const int n = nw * 32 + r * 16 + lm;
            bf16x4 pk;
            #pragma unroll
            for (int j = 0; j < 4; ++j) {
                float v = acc[m][r][j];
                pk[j] = (__bf16)v;
                s[j] += v; q[j] += v * v;
            }
            *(bf16x4*)&y0[(size_t)(bn0 + n) * NC0 + o_base + m * 16 + g * 4] = pk;
        }
        #pragma unroll
        for (int j = 0; j < 4; ++j) {
            #pragma unroll
            for (int st = 1; st < 16; st <<= 1) {
                s[j] += __shfl_xor(s[j], st);
                q[j] += __shfl_xor(q[j], st);
            }
        }
        if (lm == 0) {
            #pragma unroll
            for (int j = 0; j < 4; ++j) {
                red[0][o_base + m * 16 + g * 4 + j][nw] = s[j];
                red[1][o_base + m * 16 + g * 4 + j][nw] = q[j];
            }
        }
    }
    __syncthreads();
    if (tid < NC0) {
        atomicAdd(&sums[tid],  red[0][tid][0] + red[0][tid][1]);
        atomicAdd(&sumsq[tid], red[1][tid][0] + red[1][tid][1]);
    }
}

// ---------------------------------------------------------------------------
// Kernel 5: finalize BN stats -> scale/shift
// ---------------------------------------------------------------------------
__global__ void stats_kernel(
    const float* __restrict__ sums, const float* __restrict__ sumsq,
    const float* __restrict__ g, const float* __restrict__ be,
    float* __restrict__ scale, float* __restrict__ shift, int C)
{
    int c = blockIdx.x * blockDim.x + threadIdx.x;
    if (c < C) {
        const float invN = 1.0f / (float)NBN;
        float mean = sums[c] * invN;
        float var  = sumsq[c] * invN - mean * mean;
        float sc   = g[c] * rsqrtf(var + 1e-5f);
        scale[c] = sc;
        shift[c] = be[c] - mean * sc;
    }
}

// ---------------------------------------------------------------------------
// Kernel 6: GEMM1. B = relu(BN0(y0)) in-register. Writes y1[o][bn] bf16.
// ---------------------------------------------------------------------------
__global__ __launch_bounds__(512, 4) void gemm1_mfma(
    const __bf16* __restrict__ Wb, const __bf16* __restrict__ y0,
    const float* __restrict__ scale0, const float* __restrict__ shift0,
    __bf16* __restrict__ y1, float* __restrict__ sums, float* __restrict__ sumsq)
{
    __shared__ float red[2][NC1][4];
    const int tid = threadIdx.x;
    const int l = tid & 63, w = tid >> 6;
    const int g = l >> 4, lm = l & 15;
    const int ow = w >> 2, nw = w & 3;
    const int o_base = ow * 64;
    const int n_base = blockIdx.x * 128 + nw * 32;

    f32x4 acc[4][2] = {};

    for (int k0 = 0; k0 < NC0; k0 += 32) {
        const int kk = k0 + g * 8;
        f32x4 sc0 = *(const f32x4*)&scale0[kk];
        f32x4 sc1 = *(const f32x4*)&scale0[kk + 4];
        f32x4 sh0 = *(const f32x4*)&shift0[kk];
        f32x4 sh1 = *(const f32x4*)&shift0[kk + 4];
        bf16x8 af[4], bfr[2];
        #pragma unroll
        for (int m = 0; m < 4; ++m)
            af[m] = *(const bf16x8*)&Wb[(size_t)(o_base + m * 16 + lm) * NC0 + kk];
        #pragma unroll
        for (int r = 0; r < 2; ++r) {
            bf16x8 raw = *(const bf16x8*)&y0[(size_t)(n_base + r * 16 + lm) * NC0 + kk];
            bf16x8 bb;
            #pragma unroll
            for (int j = 0; j < 4; ++j) {
                bb[j]     = (__bf16)fmaxf((float)raw[j]     * sc0[j] + sh0[j], 0.f);
                bb[j + 4] = (__bf16)fmaxf((float)raw[j + 4] * sc1[j] + sh1[j], 0.f);
            }
            bfr[r] = bb;
        }
        #pragma unroll
        for (int m = 0; m < 4; ++m)
            #pragma unroll
            for (int r = 0; r < 2; ++r)
                acc[m][r] = __builtin_amdgcn_mfma_f32_16x16x32_bf16(af[m], bfr[r], acc[m][r], 0, 0, 0);
    }

    #pragma unroll
    for (int m = 0; m < 4; ++m) {
        float s[4] = {0.f, 0.f, 0.f, 0.f}, q[4] = {0.f, 0.f, 0.f, 0.f};
        #pragma unroll
        for (int r = 0; r < 2; ++r) {
            const int n = n_base + r * 16 + lm;
            #pragma unroll
            for (int j = 0; j < 4; ++j) {
                float v = acc[m][r][j];
                y1[(size_t)(o_base + m * 16 + g * 4 + j) * NBN + n] = (__bf16)v;
                s[j] += v; q[j] += v * v;
            }
        }
        #pragma unroll
        for (int j = 0; j < 4; ++j) {
            #pragma unroll
            for (int st = 1; st < 16; st <<= 1) {
                s[j] += __shfl_xor(s[j], st);
                q[j] += __shfl_xor(q[j], st);
            }
        }
        if (lm == 0) {
            #pragma unroll
            for (int j = 0; j < 4; ++j) {
                red[0][o_base + m * 16 + g * 4 + j][nw] = s[j];
                red[1][o_base + m * 16 + g * 4 + j][nw] = q[j];
            }
        }
    }
    __syncthreads();
    if (tid < NC1) {
        atomicAdd(&sums[tid],  red[0][tid][0] + red[0][tid][1] + red[0][tid][2] + red[0][tid][3]);
        atomicAdd(&sumsq[tid], red[1][tid][0] + red[1][tid][1] + red[1][tid][2] + red[1][tid][3]);
    }
}

// ---------------------------------------------------------------------------
// Kernel 7: apply BN1 + ReLU; y1 bf16 [o][b*N+n] -> out fp32 [b][o][n]
// ---------------------------------------------------------------------------
__global__ __launch_bounds__(256) void bnout_kernel(
    const __bf16* __restrict__ y1, const float* __restrict__ scale1,
    const float* __restrict__ shift1, float* __restrict__ out)
{
    const size_t t = (size_t)blockIdx.x * 256 + threadIdx.x;
    const size_t e = t * 8;
    const int n = (int)(e & (NPT - 1));
    const int o = (int)((e >> 13) & (NC1 - 1));
    const int b = (int)(e >> 20);
    bf16x8 v = *(const bf16x8*)&y1[(size_t)o * NBN + (size_t)b * NPT + n];
    const float s = scale1[o], sh = shift1[o];
    f32x4 r0, r1;
    #pragma unroll
    for (int j = 0; j < 4; ++j) {
        r0[j] = fmaxf((float)v[j]     * s + sh, 0.f);
        r1[j] = fmaxf((float)v[j + 4] * s + sh, 0.f);
    }
    *(f32x4*)&out[e]     = r0;
    *(f32x4*)&out[e + 4] = r1;
}

// ---------------------------------------------------------------------------
extern "C" void kernel_launch(void* const* d_in, const int* in_sizes, int n_in,
                              void* d_out, int out_size, void* d_ws, size_t ws_size,
                              hipStream_t stream)
{
    const float* xyz1    = (const float*)d_in[0];
    const float* xyz2    = (const float*)d_in[1];
    const float* points1 = (const float*)d_in[2];
    const float* points2 = (const float*)d_in[3];
    const float* w0  = (const float*)d_in[4];
    const float* g0  = (const float*)d_in[6];
    const float* be0 = (const float*)d_in[7];
    const float* w1  = (const float*)d_in[8];
    const float* g1  = (const float*)d_in[10];
    const float* be1 = (const float*)d_in[11];

    char* ws = (char*)d_ws;
    size_t off = 0;
    int*    idx3 = (int*)(ws + off);    off += (size_t)NBN * 3 * 4;        // 768 KB
    float*  wgt3 = (float*)(ws + off);  off += (size_t)NBN * 3 * 4;        // 768 KB
    __bf16* XcP1 = (__bf16*)(ws + off); off += (size_t)NBN * ND1 * 2;      // 16.8 MB
    __bf16* y0   = (__bf16*)(ws + off); off += (size_t)NBN * NC0 * 2;      // 33.6 MB
    __bf16* y1   = (__bf16*)(ws + off); off += (size_t)NC1 * NBN * 2;      // 16.8 MB
    __bf16* p2t  = (__bf16*)(ws + off); off += (size_t)NB * NS * ND2 * 2;  // 8.4 MB
    __bf16* Wb0  = (__bf16*)(ws + off); off += (size_t)NC0 * NIN * 2;      // 192 KB
    __bf16* Wb1  = (__bf16*)(ws + off); off += (size_t)NC1 * NC0 * 2;      // 64 KB
    float*  stats = (float*)(ws + off);
    float* sums0  = stats;        float* sumsq0 = stats + 256;
    float* sums1  = stats + 512;  float* sumsq1 = stats + 640;
    float* scale0 = stats + 768;  float* shift0 = stats + 1024;
    float* scale1 = stats + 1280; float* shift1 = stats + 1408;

    hipMemsetAsync(stats, 0, 768 * 4, stream);  // zero sum accumulators

    convert_w_kernel   <<<dim3(NC0 * NIN / 256), 256, 0, stream>>>(w0, w1, Wb0, Wb1);
    transpose_p2_kernel<<<dim3(NB, 128), 256, 0, stream>>>(points2, p2t);
    transpose_p1_kernel<<<dim3(NB, 256), 256, 0, stream>>>(points1, XcP1);
    knn_kernel         <<<dim3(NB, 128), 256, 0, stream>>>(xyz1, xyz2, idx3, wgt3);
    gemm0_fused        <<<dim3(NBN / 64), 512, 0, stream>>>(
        Wb0, XcP1, p2t, idx3, wgt3, y0, sums0, sumsq0);
    stats_kernel       <<<1, 256, 0, stream>>>(sums0, sumsq0, g0, be0, scale0, shift0, NC0);
    gemm1_mfma         <<<dim3(NBN / 128), 512, 0, stream>>>(Wb1, y0, scale0, shift0, y1, sums1, sumsq1);
    stats_kernel       <<<1, 128, 0, stream>>>(sums1, sumsq1, g1, be1, scale1, shift1, NC1);
    bnout_kernel       <<<dim3(NBN * NC1 / 8 / 256), 256, 0, stream>>>(y1, scale1, shift1, (float*)d_out);
}

// Round 12
// 291.486 us; speedup vs baseline: 1.1740x; 1.1251x over previous
//
#include <hip/hip_runtime.h>

// Problem constants
#define NB   8        // batch
#define NPT  8192     // N query points
#define NS   2048     // S source points
#define ND1  128      // points1 channels
#define ND2  256      // points2 channels
#define NIN  384      // concat channels
#define NC0  256      // MLP[0]
#define NC1  128      // MLP[1]
#define NBN  (NB*NPT) // 65536 total columns

typedef __bf16 bf16x8 __attribute__((ext_vector_type(8)));
typedef __bf16 bf16x4 __attribute__((ext_vector_type(4)));
typedef float  f32x4  __attribute__((ext_vector_type(4)));

// XOR swizzle for the gemm0 interp LDS tile ([64][256] bf16, 512B rows):
// applied on BOTH write and read (both-sides-or-neither).
#define SWZ(n, off) ((off) ^ (((n) & 7) << 4))

// Fragment-linear pack layout [x16][kc][g][lm][8] bf16:
//   element offset = ((x16*KC + kc)*64 + l)*8   with l = g*16 + lm  (0..63)
// (slab stride per kc = 64 lanes x 8 elems = 512. Verified by round-trip
// algebra writer<->reader; do NOT re-derive with g outside l.)

// ---------------------------------------------------------------------------
// Kernel 1: 3-NN + inverse-distance weights (known-good; full-precision keys,
// branchless index cndmask — never quantize an argmin key).
// ---------------------------------------------------------------------------
__global__ __launch_bounds__(256) void knn_kernel(
    const float* __restrict__ xyz1, const float* __restrict__ xyz2,
    int* __restrict__ idx3, float* __restrict__ wgt3)
{
    __shared__ float4 pts[NS];      // 32 KB
    __shared__ float md[64][4][3];
    __shared__ int   mi[64][4][3];

    const int b  = blockIdx.x;
    const int qt = blockIdx.y;
    const float* x2 = xyz2 + (size_t)b * 3 * NS;
    for (int s = threadIdx.x; s < NS; s += 256) {
        float x = x2[s], y = x2[NS + s], z = x2[2 * NS + s];
        pts[s] = make_float4(x, y, z, x * x + y * y + z * z);
    }
    __syncthreads();

    const int q    = threadIdx.x & 63;
    const int part = threadIdx.x >> 6;      // wave-uniform
    const int n    = qt * 64 + q;
    const float* x1 = xyz1 + (size_t)b * 3 * NPT;
    const float px = x1[n], py = x1[NPT + n], pz = x1[2 * NPT + n];
    const float qx = -2.f * px, qy = -2.f * py, qz = -2.f * pz;

    float d0 = 3e38f, d1 = 3e38f, d2 = 3e38f;
    int   i0 = 0, i1 = 0, i2 = 0;
    const int sbeg = part * (NS / 4);
    #pragma unroll 2
    for (int s = sbeg; s < sbeg + NS / 4; ++s) {
        float4 p = pts[s];
        float d = fmaf(qx, p.x, fmaf(qy, p.y, fmaf(qz, p.z, p.w)));
        bool c0 = d < d0, c1 = d < d1, c2 = d < d2;
        i2 = c1 ? i1 : (c2 ? s : i2);
        i1 = c0 ? i0 : (c1 ? s : i1);
        i0 = c0 ? s  : i0;
        d2 = fminf(fmaxf(d, d1), d2);
        d1 = fminf(fmaxf(d, d0), d1);
        d0 = fminf(d, d0);
    }
    md[q][part][0] = d0; md[q][part][1] = d1; md[q][part][2] = d2;
    mi[q][part][0] = i0; mi[q][part][1] = i1; mi[q][part][2] = i2;
    __syncthreads();

    if (threadIdx.x < 64) {
        int hp[4] = {0, 0, 0, 0};
        float rd[3]; int ri[3];
        #pragma unroll
        for (int k = 0; k < 3; ++k) {
            float best = 3.0e38f; int bl = 0;
            #pragma unroll
            for (int l = 0; l < 4; ++l) {
                float dv = md[q][l][hp[l]];
                if (dv < best) { best = dv; bl = l; }
            }
            rd[k] = best; ri[k] = mi[q][bl][hp[bl]]; hp[bl]++;
        }
        const float p1sq = px * px + py * py + pz * pz;
        float r0 = 1.0f / (rd[0] + p1sq + 1e-8f);
        float r1 = 1.0f / (rd[1] + p1sq + 1e-8f);
        float r2 = 1.0f / (rd[2] + p1sq + 1e-8f);
        float inv = 1.0f / (r0 + r1 + r2);
        size_t base = ((size_t)b * NPT + n) * 3;
        idx3[base] = ri[0]; idx3[base + 1] = ri[1]; idx3[base + 2] = ri[2];
        wgt3[base] = r0 * inv; wgt3[base + 1] = r1 * inv; wgt3[base + 2] = r2 * inv;
    }
}

// ---------------------------------------------------------------------------
// Kernel 2: transpose points2 [b][d][s] fp32 -> p2t [b][s][d] bf16.
// ---------------------------------------------------------------------------
__global__ __launch_bounds__(256) void transpose_p2_kernel(
    const float* __restrict__ p2, __bf16* __restrict__ p2t)
{
    __shared__ float tile[64][65];
    const int b  = blockIdx.x;
    const int ts = (blockIdx.y & 31) * 64;
    const int td = (blockIdx.y >> 5) * 64;
    const int sl = threadIdx.x & 63, dl = threadIdx.x >> 6;
    #pragma unroll
    for (int i = 0; i < 16; ++i)
        tile[dl + 4 * i][sl] = p2[((size_t)b * ND2 + td + dl + 4 * i) * NS + ts + sl];
    __syncthreads();
    const int dl2 = threadIdx.x & 63, sl2 = threadIdx.x >> 6;
    #pragma unroll
    for (int i = 0; i < 16; ++i)
        p2t[((size_t)b * NS + ts + sl2 + 4 * i) * ND2 + td + dl2] =
            (__bf16)tile[dl2][sl2 + 4 * i];
}

// ---------------------------------------------------------------------------
// Kernel 2b: transpose points1 -> Bp fragment-packed B-operand for gemm0.
// Bp[n16][kc(4)][g][lm][8]: value X[n = n16*16+lm][c = kc*32 + g*8 + e].
// ---------------------------------------------------------------------------
__global__ __launch_bounds__(256) void transpose_p1_kernel(
    const float* __restrict__ p1, __bf16* __restrict__ Bp)
{
    __shared__ float tile[64][65];
    const int b  = blockIdx.x;
    const int tn = (blockIdx.y & 127) * 64;
    const int tc = (blockIdx.y >> 7) * 64;
    const int sl = threadIdx.x & 63, dl = threadIdx.x >> 6;
    #pragma unroll
    for (int i = 0; i < 16; ++i)
        tile[dl + 4 * i][sl] = p1[((size_t)b * ND1 + tc + dl + 4 * i) * NPT + tn + sl];
    __syncthreads();
    const int n_local = threadIdx.x >> 2, c16 = threadIdx.x & 3;
    bf16x8 v0, v1;
    #pragma unroll
    for (int k = 0; k < 8; ++k) {
        v0[k] = (__bf16)tile[c16 * 16 + k][n_local];
        v1[k] = (__bf16)tile[c16 * 16 + 8 + k][n_local];
    }
    const int n16 = (int)(((size_t)b * NPT + tn + n_local) >> 4);
    const int lm  = n_local & 15;
    const int kc  = (tc >> 5) + (c16 >> 1);
    const int g0  = (c16 & 1) * 2;
    // elem offset ((n16*4 + kc)*64 + g*16 + lm)*8
    __bf16* base = Bp + (((size_t)n16 * 4 + kc) * 64 + lm) * 8;
    *(bf16x8*)(base + g0 * 128)       = v0;   // g0   -> +g0*16*8
    *(bf16x8*)(base + (g0 + 1) * 128) = v1;   // g0+1
}

// ---------------------------------------------------------------------------
// Kernel 3: pack weights into fragment-linear bf16 layouts.
// Ap0[o16(16)][kc(12)][g][lm][8] ; Ap1[o16(8)][kc(8)][g][lm][8]
// ---------------------------------------------------------------------------
__global__ __launch_bounds__(64) void pack_w_kernel(
    const float* __restrict__ w0, const float* __restrict__ w1,
    __bf16* __restrict__ Ap0, __bf16* __restrict__ Ap1)
{
    const int o  = blockIdx.x;          // 0..255
    const int k8 = threadIdx.x;         // 0..63
    if (k8 < 48) {
        const float* src = w0 + (size_t)o * NIN + k8 * 8;
        bf16x8 v;
        #pragma unroll
        for (int e = 0; e < 8; ++e) v[e] = (__bf16)src[e];
        *(bf16x8*)&Ap0[((((o >> 4) * 12 + (k8 >> 2)) * 4 + (k8 & 3)) * 16 + (o & 15)) * 8] = v;
    }
    if (o < NC1 && k8 < 32) {
        const float* src = w1 + (size_t)o * NC0 + k8 * 8;
        bf16x8 v;
        #pragma unroll
        for (int e = 0; e < 8; ++e) v[e] = (__bf16)src[e];
        *(bf16x8*)&Ap1[((((o >> 4) * 8 + (k8 >> 2)) * 4 + (k8 & 3)) * 16 + (o & 15)) * 8] = v;
    }
}

// ---------------------------------------------------------------------------
// Kernel 4: GEMM0 + fused interp. All global GEMM operands fragment-packed
// (wave loads contiguous 1KB: slab stride 64 lanes). Interp half via
// swizzled LDS. y0 written packed as Yp[n16][kc(8)][g][lm][8].
// ---------------------------------------------------------------------------
__global__ __launch_bounds__(512, 4) void gemm0_fused(
    const __bf16* __restrict__ Ap0, const __bf16* __restrict__ Bp,
    const __bf16* __restrict__ p2t,
    const int* __restrict__ idx3, const float* __restrict__ wgt3,
    __bf16* __restrict__ Yp, float* __restrict__ sums, float* __restrict__ sumsq)
{
    __shared__ char Bs[64 * ND2 * 2];      // 32 KB, [n][256] bf16 swizzled
    __shared__ float red[2][NC0][2];       // 4 KB

    const int tid = threadIdx.x;
    const int bx  = blockIdx.x;
    const int bn0 = bx * 64;
    const int b   = bn0 / NPT;

    // gather setup
    const int ng   = tid >> 3;             // 0..63
    const int part = tid & 7;              // 0..7
    const size_t base3 = (size_t)(bn0 + ng) * 3;
    const int gi0 = idx3[base3], gi1 = idx3[base3 + 1], gi2 = idx3[base3 + 2];
    const float gw0 = wgt3[base3], gw1 = wgt3[base3 + 1], gw2 = wgt3[base3 + 2];
    const __bf16* r0 = p2t + ((size_t)b * NS + gi0) * ND2;
    const __bf16* r1 = p2t + ((size_t)b * NS + gi1) * ND2;
    const __bf16* r2 = p2t + ((size_t)b * NS + gi2) * ND2;

    // MFMA lane mapping
    const int l = tid & 63, w = tid >> 6;
    const int g = l >> 4, lm = l & 15;
    const int ow = w >> 1, nw = w & 1;     // 4 o-waves x 2 n-waves
    const int o_base = ow * 64;

    f32x4 acc[4][2] = {};

    // ---- A1: issue first 6 gathers ----
    bf16x8 rawA0, rawA1, rawA2, rawB0, rawB1, rawB2;
    {
        const int d0 = part * 32;
        rawA0 = *(const bf16x8*)(r0 + d0);     rawA1 = *(const bf16x8*)(r1 + d0);
        rawA2 = *(const bf16x8*)(r2 + d0);
        rawB0 = *(const bf16x8*)(r0 + d0 + 8); rawB1 = *(const bf16x8*)(r1 + d0 + 8);
        rawB2 = *(const bf16x8*)(r2 + d0 + 8);
    }

    // ---- B1: MFMA k = 0..63, packed global loads ----
    #pragma unroll
    for (int k0 = 0; k0 < 64; k0 += 32) {
        const int kc = k0 >> 5;
        bf16x8 af[4], bfr[2];
        #pragma unroll
        for (int m = 0; m < 4; ++m)
            af[m] = *(const bf16x8*)&Ap0[(((ow * 4 + m) * 12 + kc) * 64 + l) * 8];
        #pragma unroll
        for (int r = 0; r < 2; ++r)
            bfr[r] = *(const bf16x8*)&Bp[((((size_t)bx * 4 + nw * 2 + r) * 4 + kc) * 64 + l) * 8];
        #pragma unroll
        for (int m = 0; m < 4; ++m)
            #pragma unroll
            for (int r = 0; r < 2; ++r)
                acc[m][r] = __builtin_amdgcn_mfma_f32_16x16x32_bf16(af[m], bfr[r], acc[m][r], 0, 0, 0);
    }

    // ---- C1: blend + LDS write; A2: issue next 6 gathers ----
    {
        bf16x8 v0, v1;
        #pragma unroll
        for (int j = 0; j < 8; ++j) {
            v0[j] = (__bf16)(gw0 * (float)rawA0[j] + gw1 * (float)rawA1[j] + gw2 * (float)rawA2[j]);
            v1[j] = (__bf16)(gw0 * (float)rawB0[j] + gw1 * (float)rawB1[j] + gw2 * (float)rawB2[j]);
        }
        const int d0 = part * 32;
        *(bf16x8*)(Bs + ng * (ND2 * 2) + SWZ(ng, d0 * 2))       = v0;
        *(bf16x8*)(Bs + ng * (ND2 * 2) + SWZ(ng, (d0 + 8) * 2)) = v1;
    }
    {
        const int d0 = part * 32 + 16;
        rawA0 = *(const bf16x8*)(r0 + d0);     rawA1 = *(const bf16x8*)(r1 + d0);
        rawA2 = *(const bf16x8*)(r2 + d0);
        rawB0 = *(const bf16x8*)(r0 + d0 + 8); rawB1 = *(const bf16x8*)(r1 + d0 + 8);
        rawB2 = *(const bf16x8*)(r2 + d0 + 8);
    }

    // ---- B2: MFMA k = 64..127, packed global loads ----
    #pragma unroll
    for (int k0 = 64; k0 < 128; k0 += 32) {
        const int kc = k0 >> 5;
        bf16x8 af[4], bfr[2];
        #pragma unroll
        for (int m = 0; m < 4; ++m)
            af[m] = *(const bf16x8*)&Ap0[(((ow * 4 + m) * 12 + kc) * 64 + l) * 8];
        #pragma unroll
        for (int r = 0; r < 2; ++r)
            bfr[r] = *(const bf16x8*)&Bp[((((size_t)bx * 4 + nw * 2 + r) * 4 + kc) * 64 + l) * 8];
        #pragma unroll
        for (int m = 0; m < 4; ++m)
            #pragma unroll
            for (int r = 0; r < 2; ++r)
                acc[m][r] = __builtin_amdgcn_mfma_f32_16x16x32_bf16(af[m], bfr[r], acc[m][r], 0, 0, 0);
    }

    // ---- C2: blend + LDS write ----
    {
        bf16x8 v0, v1;
        #pragma unroll
        for (int j = 0; j < 8; ++j) {
            v0[j] = (__bf16)(gw0 * (float)rawA0[j] + gw1 * (float)rawA1[j] + gw2 * (float)rawA2[j]);
            v1[j] = (__bf16)(gw0 * (float)rawB0[j] + gw1 * (float)rawB1[j] + gw2 * (float)rawB2[j]);
        }
        const int d0 = part * 32 + 16;
        *(bf16x8*)(Bs + ng * (ND2 * 2) + SWZ(ng, d0 * 2))       = v0;
        *(bf16x8*)(Bs + ng * (ND2 * 2) + SWZ(ng, (d0 + 8) * 2)) = v1;
    }
    __syncthreads();

    // ---- D: MFMA k = 128..383, A packed global, B from swizzled LDS ----
    #pragma unroll
    for (int k0 = 128; k0 < NIN; k0 += 32) {
        const int kc = k0 >> 5;
        const int kd = k0 - 128 + g * 8;
        bf16x8 af[4], bfr[2];
        #pragma unroll
        for (int m = 0; m < 4; ++m)
            af[m] = *(const bf16x8*)&Ap0[(((ow * 4 + m) * 12 + kc) * 64 + l) * 8];
        #pragma unroll
        for (int r = 0; r < 2; ++r) {
            const int n_lds = nw * 32 + r * 16 + lm;
            bfr[r] = *(const bf16x8*)(Bs + n_lds * (ND2 * 2) + SWZ(n_lds, kd * 2));
        }
        #pragma unroll
        for (int m = 0; m < 4; ++m)
            #pragma unroll
            for (int r = 0; r < 2; ++r)
                acc[m][r] = __builtin_amdgcn_mfma_f32_16x16x32_bf16(af[m], bfr[r], acc[m][r], 0, 0, 0);
    }

    // ---- epilogue: packed y0 write (coalesced) + stats ----
    #pragma unroll
    for (int m = 0; m < 4; ++m) {
        float s[4] = {0.f, 0.f, 0.f, 0.f}, q[4] = {0.f, 0.f, 0.f, 0.f};
        const int kc = ow * 2 + (m >> 1);
        const int g2 = (m & 1) * 2 + (g >> 1);
        #pragma unroll
        for (int r = 0; r < 2; ++r) {
            const int n16 = bx * 4 + nw * 2 + r;
            bf16x4 pk;
            #pragma unroll
            for (int j = 0; j < 4; ++j) {
                float v = acc[m][r][j];
                pk[j] = (__bf16)v;
                s[j] += v; q[j] += v * v;
            }
            // stores value (o = ow*64+m*16+g*4+j, n = n16*16+lm) at
            // elem off ((n16*8 + kc)*64 + g2*16 + lm)*8 + (g&1)*4 + j
            *(bf16x4*)&Yp[(((size_t)n16 * 8 + kc) * 64 + g2 * 16 + lm) * 8 + (g & 1) * 4] = pk;
        }
        #pragma unroll
        for (int j = 0; j < 4; ++j) {
            #pragma unroll
            for (int st = 1; st < 16; st <<= 1) {
                s[j] += __shfl_xor(s[j], st);
                q[j] += __shfl_xor(q[j], st);
            }
        }
        if (lm == 0) {
            #pragma unroll
            for (int j = 0; j < 4; ++j) {
                red[0][o_base + m * 16 + g * 4 + j][nw] = s[j];
                red[1][o_base + m * 16 + g * 4 + j][nw] = q[j];
            }
        }
    }
    __syncthreads();
    if (tid < NC0) {
        atomicAdd(&sums[tid],  red[0][tid][0] + red[0][tid][1]);
        atomicAdd(&sumsq[tid], red[1][tid][0] + red[1][tid][1]);
    }
}

// ---------------------------------------------------------------------------
// Kernel 5: finalize BN stats -> scale/shift
// ---------------------------------------------------------------------------
__global__ void stats_kernel(
    const float* __restrict__ sums, const float* __restrict__ sumsq,
    const float* __restrict__ g, const float* __restrict__ be,
    float* __restrict__ scale, float* __restrict__ shift, int C)
{
    int c = blockIdx.x * blockDim.x + threadIdx.x;
    if (c < C) {
        const float invN = 1.0f / (float)NBN;
        float mean = sums[c] * invN;
        float var  = sumsq[c] * invN - mean * mean;
        float sc   = g[c] * rsqrtf(var + 1e-5f);
        scale[c] = sc;
        shift[c] = be[c] - mean * sc;
    }
}

// ---------------------------------------------------------------------------
// Kernel 6: GEMM1. A/B from packed layouts; B = relu(BN0(.)) in-register.
// Writes y1[o][bn] bf16 (bnout's coalesced layout).
// ---------------------------------------------------------------------------
__global__ __launch_bounds__(512, 4) void gemm1_mfma(
    const __bf16* __restrict__ Ap1, const __bf16* __restrict__ Yp,
    const float* __restrict__ scale0, const float* __restrict__ shift0,
    __bf16* __restrict__ y1, float* __restrict__ sums, float* __restrict__ sumsq)
{
    __shared__ float red[2][NC1][4];
    const int tid = threadIdx.x;
    const int bx  = blockIdx.x;
    const int l = tid & 63, w = tid >> 6;
    const int g = l >> 4, lm = l & 15;
    const int ow = w >> 2, nw = w & 3;
    const int o_base = ow * 64;
    const int n_base = bx * 128 + nw * 32;

    f32x4 acc[4][2] = {};

    for (int k0 = 0; k0 < NC0; k0 += 32) {
        const int kc = k0 >> 5;
        const int kk = k0 + g * 8;
        f32x4 sc0 = *(const f32x4*)&scale0[kk];
        f32x4 sc1 = *(const f32x4*)&scale0[kk + 4];
        f32x4 sh0 = *(const f32x4*)&shift0[kk];
        f32x4 sh1 = *(const f32x4*)&shift0[kk + 4];
        bf16x8 af[4], bfr[2];
        #pragma unroll
        for (int m = 0; m < 4; ++m)
            af[m] = *(const bf16x8*)&Ap1[(((ow * 4 + m) * 8 + kc) * 64 + l) * 8];
        #pragma unroll
        for (int r = 0; r < 2; ++r) {
            bf16x8 raw = *(const bf16x8*)&Yp[((((size_t)bx * 8 + nw * 2 + r) * 8 + kc) * 64 + l) * 8];
            bf16x8 bb;
            #pragma unroll
            for (int j = 0; j < 4; ++j) {
                bb[j]     = (__bf16)fmaxf((float)raw[j]     * sc0[j] + sh0[j], 0.f);
                bb[j + 4] = (__bf16)fmaxf((float)raw[j + 4] * sc1[j] + sh1[j], 0.f);
            }
            bfr[r] = bb;
        }
        #pragma unroll
        for (int m = 0; m < 4; ++m)
            #pragma unroll
            for (int r = 0; r < 2; ++r)
                acc[m][r] = __builtin_amdgcn_mfma_f32_16x16x32_bf16(af[m], bfr[r], acc[m][r], 0, 0, 0);
    }

    #pragma unroll
    for (int m = 0; m < 4; ++m) {
        float s[4] = {0.f, 0.f, 0.f, 0.f}, q[4] = {0.f, 0.f, 0.f, 0.f};
        #pragma unroll
        for (int r = 0; r < 2; ++r) {
            const int n = n_base + r * 16 + lm;
            #pragma unroll
            for (int j = 0; j < 4; ++j) {
                float v = acc[m][r][j];
                y1[(size_t)(o_base + m * 16 + g * 4 + j) * NBN + n] = (__bf16)v;
                s[j] += v; q[j] += v * v;
            }
        }
        #pragma unroll
        for (int j = 0; j < 4; ++j) {
            #pragma unroll
            for (int st = 1; st < 16; st <<= 1) {
                s[j] += __shfl_xor(s[j], st);
                q[j] += __shfl_xor(q[j], st);
            }
        }
        if (lm == 0) {
            #pragma unroll
            for (int j = 0; j < 4; ++j) {
                red[0][o_base + m * 16 + g * 4 + j][nw] = s[j];
                red[1][o_base + m * 16 + g * 4 + j][nw] = q[j];
            }
        }
    }
    __syncthreads();
    if (tid < NC1) {
        atomicAdd(&sums[tid],  red[0][tid][0] + red[0][tid][1] + red[0][tid][2] + red[0][tid][3]);
        atomicAdd(&sumsq[tid], red[1][tid][0] + red[1][tid][1] + red[1][tid][2] + red[1][tid][3]);
    }
}

// ---------------------------------------------------------------------------
// Kernel 7: apply BN1 + ReLU; y1 bf16 [o][b*N+n] -> out fp32 [b][o][n]
// ---------------------------------------------------------------------------
__global__ __launch_bounds__(256) void bnout_kernel(
    const __bf16* __restrict__ y1, const float* __restrict__ scale1,
    const float* __restrict__ shift1, float* __restrict__ out)
{
    const size_t t = (size_t)blockIdx.x * 256 + threadIdx.x;
    const size_t e = t * 8;
    const int n = (int)(e & (NPT - 1));
    const int o = (int)((e >> 13) & (NC1 - 1));
    const int b = (int)(e >> 20);
    bf16x8 v = *(const bf16x8*)&y1[(size_t)o * NBN + (size_t)b * NPT + n];
    const float s = scale1[o], sh = shift1[o];
    f32x4 r0, r1;
    #pragma unroll
    for (int j = 0; j < 4; ++j) {
        r0[j] = fmaxf((float)v[j]     * s + sh, 0.f);
        r1[j] = fmaxf((float)v[j + 4] * s + sh, 0.f);
    }
    *(f32x4*)&out[e]     = r0;
    *(f32x4*)&out[e + 4] = r1;
}

// ---------------------------------------------------------------------------
extern "C" void kernel_launch(void* const* d_in, const int* in_sizes, int n_in,
                              void* d_out, int out_size, void* d_ws, size_t ws_size,
                              hipStream_t stream)
{
    const float* xyz1    = (const float*)d_in[0];
    const float* xyz2    = (const float*)d_in[1];
    const float* points1 = (const float*)d_in[2];
    const float* points2 = (const float*)d_in[3];
    const float* w0  = (const float*)d_in[4];
    const float* g0  = (const float*)d_in[6];
    const float* be0 = (const float*)d_in[7];
    const float* w1  = (const float*)d_in[8];
    const float* g1  = (const float*)d_in[10];
    const float* be1 = (const float*)d_in[11];

    char* ws = (char*)d_ws;
    size_t off = 0;
    int*    idx3 = (int*)(ws + off);    off += (size_t)NBN * 3 * 4;        // 768 KB
    float*  wgt3 = (float*)(ws + off);  off += (size_t)NBN * 3 * 4;        // 768 KB
    __bf16* Bp   = (__bf16*)(ws + off); off += (size_t)NBN * ND1 * 2;      // 16.8 MB
    __bf16* Yp   = (__bf16*)(ws + off); off += (size_t)NBN * NC0 * 2;      // 33.6 MB
    __bf16* y1   = (__bf16*)(ws + off); off += (size_t)NC1 * NBN * 2;      // 16.8 MB
    __bf16* p2t  = (__bf16*)(ws + off); off += (size_t)NB * NS * ND2 * 2;  // 8.4 MB
    __bf16* Ap0  = (__bf16*)(ws + off); off += (size_t)NC0 * NIN * 2;      // 192 KB
    __bf16* Ap1  = (__bf16*)(ws + off); off += (size_t)NC1 * NC0 * 2;      // 64 KB
    float*  stats = (float*)(ws + off);
    float* sums0  = stats;        float* sumsq0 = stats + 256;
    float* sums1  = stats + 512;  float* sumsq1 = stats + 640;
    float* scale0 = stats + 768;  float* shift0 = stats + 1024;
    float* scale1 = stats + 1280; float* shift1 = stats + 1408;

    hipMemsetAsync(stats, 0, 768 * 4, stream);  // zero sum accumulators

    pack_w_kernel      <<<dim3(NC0), 64, 0, stream>>>(w0, w1, Ap0, Ap1);
    transpose_p2_kernel<<<dim3(NB, 128), 256, 0, stream>>>(points2, p2t);
    transpose_p1_kernel<<<dim3(NB, 256), 256, 0, stream>>>(points1, Bp);
    knn_kernel         <<<dim3(NB, 128), 256, 0, stream>>>(xyz1, xyz2, idx3, wgt3);
    gemm0_fused        <<<dim3(NBN / 64), 512, 0, stream>>>(
        Ap0, Bp, p2t, idx3, wgt3, Yp, sums0, sumsq0);
    stats_kernel       <<<1, 256, 0, stream>>>(sums0, sumsq0, g0, be0, scale0, shift0, NC0);
    gemm1_mfma         <<<dim3(NBN / 128), 512, 0, stream>>>(Ap1, Yp, scale0, shift0, y1, sums1, sumsq1);
    stats_kernel       <<<1, 128, 0, stream>>>(sums1, sumsq1, g1, be1, scale1, shift1, NC1);
    bnout_kernel       <<<dim3(NBN * NC1 / 8 / 256), 256, 0, stream>>>(y1, scale1, shift1, (float*)d_out);
}